// Round 1
// 982.682 us; speedup vs baseline: 1.0025x; 1.0025x over previous
//
#include <hip/hip_runtime.h>

// ---------------------------------------------------------------------------
// ClassificationNCA — Round 5: register-pipelined weight-tile loads.
// R4 structure kept (direct perception A-frags, pre-split bf16 hi/lo LDS
// planes, 40960 B LDS, 2 barriers/step). New: depth-1/2 register double-
// buffering of pw1/pw2/pw3 B-fragments so global loads are issued one MFMA
// cluster (or one full nc-iteration) ahead of use; s_setprio around MFMA
// clusters; c0/c1 chains interleaved (per-acc order unchanged -> bit-identical
// numerics); fire-mask Threefry hoisted to fill prologue load shadow.
// ---------------------------------------------------------------------------

#define ROTL32(x, d) (((x) << (d)) | ((x) >> (32 - (d))))

struct U2 { unsigned a, b; };

__host__ __device__ inline U2 tf2x32(unsigned k0, unsigned k1, unsigned c0, unsigned c1) {
  unsigned ks2 = k0 ^ k1 ^ 0x1BD11BDAu;
  unsigned x0 = c0 + k0;
  unsigned x1 = c1 + k1;
#define TF_ROUND4(r0, r1, r2, r3)                                              \
  x0 += x1; x1 = ROTL32(x1, r0); x1 ^= x0;                                     \
  x0 += x1; x1 = ROTL32(x1, r1); x1 ^= x0;                                     \
  x0 += x1; x1 = ROTL32(x1, r2); x1 ^= x0;                                     \
  x0 += x1; x1 = ROTL32(x1, r3); x1 ^= x0;
  TF_ROUND4(13, 15, 26, 6)
  x0 += k1;  x1 += ks2 + 1u;
  TF_ROUND4(17, 29, 16, 24)
  x0 += ks2; x1 += k0 + 2u;
  TF_ROUND4(13, 15, 26, 6)
  x0 += k0;  x1 += k1 + 3u;
  TF_ROUND4(17, 29, 16, 24)
  x0 += k1;  x1 += ks2 + 4u;
  TF_ROUND4(13, 15, 26, 6)
  x0 += ks2; x1 += k0 + 5u;
#undef TF_ROUND4
  U2 r; r.a = x0; r.b = x1; return r;
}

__device__ inline float erfinv_xla(float x) {
  float w = -log1pf(-x * x);
  float p;
  if (w < 5.0f) {
    w -= 2.5f;
    p = 2.81022636e-08f;
    p = fmaf(p, w, 3.43273939e-07f);
    p = fmaf(p, w, -3.5233877e-06f);
    p = fmaf(p, w, -4.39150654e-06f);
    p = fmaf(p, w, 0.00021858087f);
    p = fmaf(p, w, -0.00125372503f);
    p = fmaf(p, w, -0.00417768164f);
    p = fmaf(p, w, 0.246640727f);
    p = fmaf(p, w, 1.50140941f);
  } else {
    w = sqrtf(w) - 3.0f;
    p = -0.000200214257f;
    p = fmaf(p, w, 0.000100950558f);
    p = fmaf(p, w, 0.00134934322f);
    p = fmaf(p, w, -0.00367342844f);
    p = fmaf(p, w, 0.00573950773f);
    p = fmaf(p, w, -0.0076224613f);
    p = fmaf(p, w, 0.00943887047f);
    p = fmaf(p, w, 1.00167406f);
    p = fmaf(p, w, 2.83297682f);
  }
  return p * x;
}

__device__ inline float leaky(float v) { return v >= 0.0f ? v : 0.01f * v; }

typedef __attribute__((ext_vector_type(8))) short bf16x8;
typedef __attribute__((ext_vector_type(4))) float f32x4;

__host__ __device__ inline unsigned short bf16_rne(float x) {
  unsigned u = __float_as_uint(x);
  return (unsigned short)((u + 0x7FFFu + ((u >> 16) & 1u)) >> 16);
}

__device__ inline void split8(const float v[8], bf16x8& hi, bf16x8& lo) {
#pragma unroll
  for (int j = 0; j < 8; ++j) {
    unsigned short h = bf16_rne(v[j]);
    float hf = __uint_as_float(((unsigned)h) << 16);
    unsigned short l = bf16_rne(v[j] - hf);
    hi[j] = (short)h;
    lo[j] = (short)l;
  }
}

// XOR swizzles: 16B groups; 4-group window (64B rows) / 8-group window (256B).
__device__ inline int swz64(int m, int off) {
  int g = (off >> 4) ^ (m & 3);
  return (g << 4) | (off & 15);
}
__device__ inline int swz256(int m, int off) {
  int g = off >> 4;
  g = (g & ~7) | ((g ^ (m & 7)) & 7);
  return (g << 4) | (off & 15);
}

#define MFMA(a, b, c) __builtin_amdgcn_mfma_f32_16x16x32_bf16((a), (b), (c), 0, 0, 0)

// ---------------------------------------------------------------------------
// Weight prep: fragment-major packed B-tiles (1 KB/tile), as in R3/R4.
// ---------------------------------------------------------------------------
__global__ void prep_weights(const float* __restrict__ w1, const float* __restrict__ w2,
                             const float* __restrict__ w3,
                             unsigned short* __restrict__ pw1,
                             unsigned short* __restrict__ pw2,
                             unsigned short* __restrict__ pw3) {
  int i = blockIdx.x * 256 + threadIdx.x;
  int e = i & 511, L = e >> 3, j = e & 7;
  int kq = (L >> 4) * 8 + j;   // k within 32-chunk
  int ln = L & 15;             // n within 16-tile
  if (i < 96 * 512) {          // pw1: [nc(8)][kc(3)][f(4)]
    int tile = i >> 9;
    int f = tile & 3, kc = (tile >> 2) % 3, nc = tile / 12;
    int n = nc * 32 + (f >> 1) * 16 + ln;
    int src;
    if (kc == 0)      src = (kq < 29) ? kq : -1;
    else if (kc == 1) src = (kq < 29) ? 29 + kq : ((kq == 29) ? 87 : -1);
    else              src = (kq < 29) ? 58 + kq : -1;
    float v = (src >= 0) ? w1[n * 88 + src] : 0.0f;
    unsigned short h = bf16_rne(v);
    pw1[i] = (f & 1) ? bf16_rne(v - __uint_as_float(((unsigned)h) << 16)) : h;
  }
  if (i < 128 * 512) {         // pw2: [nc(8)][t(8)][h,l]
    int tile = i >> 9;
    int hl = tile & 1, t = (tile >> 1) & 7, nc = tile >> 4;
    int n = t * 16 + ln;
    int k = nc * 32 + kq;
    float v = w2[n * 256 + k];
    unsigned short h = bf16_rne(v);
    pw2[i] = hl ? bf16_rne(v - __uint_as_float(((unsigned)h) << 16)) : h;
  }
  if (i < 16 * 512) {          // pw3: [kc(4)][f(4)]
    int tile = i >> 9;
    int f = tile & 3, kc = tile >> 2;
    int n = (f >> 1) * 16 + ln;
    int k = kc * 32 + kq;
    float v = (n < 29) ? w3[n * 128 + k] : 0.0f;
    unsigned short h = bf16_rne(v);
    pw3[i] = (f & 1) ? bf16_rne(v - __uint_as_float(((unsigned)h) << 16)) : h;
  }
}

// ---------------------------------------------------------------------------
__global__ void init_state(const float* __restrict__ x, float* __restrict__ s0,
                           float* __restrict__ s1, unsigned hk0, unsigned hk1) {
  int idx = blockIdx.x * 256 + threadIdx.x;
  if (idx >= 16 * 29 * 4096) return;
  int pix = idx & 4095;
  int c = (idx >> 12) % 29;
  int b = idx / (4096 * 29);
  float v;
  if (c < 3) {
    v = x[(b * 3 + c) * 4096 + pix];
    s1[idx] = v;
  } else if (c < 19) {
    int ch = c - 3;
    int i = (b * 16 + ch) * 4096 + pix;
    const int half = 131072;
    unsigned bits;
    if (i < half) bits = tf2x32(hk0, hk1, (unsigned)i, (unsigned)(i + half)).a;
    else          bits = tf2x32(hk0, hk1, (unsigned)(i - half), (unsigned)i).b;
    float f = __uint_as_float((bits >> 9) | 0x3F800000u) - 1.0f;
    const float lo = -0x1.fffffep-1f;
    float u = fmaxf(lo, fmaf(f, 2.0f, lo));
    v = fmaf(0.225f, 1.41421356237f * erfinv_xla(u), 0.5f);
  } else {
    v = 0.0f;
  }
  s0[idx] = v;
}

// ---------------------------------------------------------------------------
// One NCA step. LDS map (bytes), total 40960:
//   [0     ..  4096)  h1h  ushort[64][32], row 64 B, swz64
//   [4096  ..  8192)  h1l  ushort[64][32]
//   [8192  .. 24576)  h2h  ushort[64][128], row 256 B, swz256
//   [24576 .. 40960)  h2l  ushort[64][128]
//   sS halo float[29][stride 109] overlays [8192, 20836).
// ---------------------------------------------------------------------------
__global__ __launch_bounds__(256, 4) void nca_step(
    const float* __restrict__ sin_, float* __restrict__ sout,
    const unsigned short* __restrict__ pw1, const float* __restrict__ b1,
    const unsigned short* __restrict__ pw2, const unsigned short* __restrict__ pw3,
    float tval, unsigned fk0, unsigned fk1) {
  __shared__ __align__(16) char lds[40960];
  char* h1h = lds;
  char* h1l = lds + 4096;
  char* h2h = lds + 8192;
  char* h2l = lds + 24576;
  float* sS = (float*)(lds + 8192);   // channel stride 109 floats (bank-spread)

  const int tid = threadIdx.x;
  const int w = tid >> 6;
  const int L = tid & 63;
  const int lane16 = L & 15;
  const int quad = L >> 4;
  const int b = blockIdx.z;
  const int ty0 = blockIdx.y * 4;
  const int tx0 = blockIdx.x * 16;
  const float* sb = sin_ + b * 29 * 4096;

  // --- P1: halo load (29 ch x 6 rows x 18 cols, zero-padded) ---
  for (int l = tid; l < 29 * 108; l += 256) {
    int c = l / 108;
    int rem = l - c * 108;
    int r = rem / 18;
    int x = rem - r * 18;
    int gy = ty0 - 1 + r, gx = tx0 - 1 + x;
    float v = 0.0f;
    if ((unsigned)gy < 64u && (unsigned)gx < 64u) v = sb[c * 4096 + gy * 64 + gx];
    sS[c * 109 + r * 18 + x] = v;
  }
  __syncthreads();

  // --- A1 fragments directly from halo (permuted K: ps | px,t | py) ---
  const int am = w * 16 + lane16;
  bf16x8 a1h[3], a1l[3];
  {
    float vps[8], vpx[8], vpy[8];
#pragma unroll
    for (int j = 0; j < 8; ++j) {
      int c = quad * 8 + j;
      int cc = (c < 29) ? c : 0;
      const float* S = sS + cc * 109 + (w + 1) * 18 + (lane16 + 1);
      float m00 = S[-19], m01 = S[-18], m02 = S[-17];
      float m10 = S[-1],  m11 = S[0],   m12 = S[1];
      float m20 = S[17],  m21 = S[18],  m22 = S[19];
      bool valid = (c < 29);
      vps[j] = valid ? m11 : 0.0f;
      float px = ((m02 - m00) + 2.0f * (m12 - m10) + (m22 - m20)) * 0.125f;
      float py = ((m20 + 2.0f * m21 + m22) - (m00 + 2.0f * m01 + m02)) * 0.125f;
      vpx[j] = valid ? px : ((c == 29) ? tval : 0.0f);
      vpy[j] = valid ? py : 0.0f;
    }
    split8(vps, a1h[0], a1l[0]);
    split8(vpx, a1h[1], a1l[1]);
    split8(vpy, a1h[2], a1l[2]);
  }
  __syncthreads();  // sS dead -> h2 region reusable

  const int L16 = L * 16;

  // --- prologue: issue pw1[nc=0,kc=0] tile loads (depth-1 pipeline seed) ---
  bf16x8 n1a, n1b, n1c, n1d;
  {
    const char* g = (const char*)pw1;
    n1a = *(const bf16x8*)(g + L16);
    n1b = *(const bf16x8*)(g + 1024 + L16);
    n1c = *(const bf16x8*)(g + 2048 + L16);
    n1d = *(const bf16x8*)(g + 3072 + L16);
  }

  // --- fire mask (pure VALU; hoisted here to fill prologue load shadow) ---
  float fire;
  {
    int i = b * 4096 + (ty0 + w) * 64 + (tx0 + lane16);
    unsigned bits;
    if (i < 32768) bits = tf2x32(fk0, fk1, (unsigned)i, (unsigned)(i + 32768)).a;
    else           bits = tf2x32(fk0, fk1, (unsigned)(i - 32768), (unsigned)i).b;
    fire = (bits & 0x80000000u) ? 0.0f : 1.0f;
  }

  // --- fused layer1 -> layer2 over 8 n-chunks of 32 ---
  f32x4 acc2[8];
#pragma unroll
  for (int t = 0; t < 8; ++t) acc2[t] = (f32x4){0.f, 0.f, 0.f, 0.f};

#pragma unroll 1
  for (int nc = 0; nc < 8; ++nc) {
    f32x4 c0 = (f32x4){0.f, 0.f, 0.f, 0.f};
    f32x4 c1 = (f32x4){0.f, 0.f, 0.f, 0.f};
#pragma unroll
    for (int kc = 0; kc < 3; ++kc) {
      // consume the preloaded tile; issue the next one first.
      bf16x8 w1a = n1a, w1b = n1b, w1cc = n1c, w1d = n1d;
      {
        // kc<2: next kc of this nc.  kc==2: kc=0 of the NEXT nc (long cover:
        // the loads stay in flight across the whole h1 epilogue + t-loop).
        const int nt = (kc < 2) ? (nc * 3 + kc + 1) : (((nc + 1) & 7) * 3);
        const char* g = (const char*)pw1 + nt * 4096;
        n1a = *(const bf16x8*)(g + L16);
        n1b = *(const bf16x8*)(g + 1024 + L16);
        n1c = *(const bf16x8*)(g + 2048 + L16);
        n1d = *(const bf16x8*)(g + 3072 + L16);
      }
      __builtin_amdgcn_s_setprio(1);
      // c0/c1 chains interleaved; per-accumulator MFMA order unchanged
      // (hh, h*bl, l*bh) -> bit-identical to R4.
      c0 = MFMA(a1h[kc], w1a, c0);
      c1 = MFMA(a1h[kc], w1cc, c1);
      c0 = MFMA(a1h[kc], w1b, c0);
      c1 = MFMA(a1h[kc], w1d, c1);
      c0 = MFMA(a1l[kc], w1a, c0);
      c1 = MFMA(a1l[kc], w1cc, c1);
      __builtin_amdgcn_s_setprio(0);
    }

    // pw2 pipeline (depth 2): issue t=0,1 tiles BEFORE the h1 epilogue so the
    // ~300-cycle split/LDS round-trip covers their latency.
    const char* g2 = (const char*)pw2 + nc * 16384;
    bf16x8 p0h = *(const bf16x8*)(g2 + L16);
    bf16x8 p0l = *(const bf16x8*)(g2 + 1024 + L16);
    bf16x8 p1h = *(const bf16x8*)(g2 + 2048 + L16);
    bf16x8 p1l = *(const bf16x8*)(g2 + 3072 + L16);

    // bias + leaky + SPLIT -> h1 hi/lo planes (wave-private rows)
    float bv0 = b1[nc * 32 + lane16];
    float bv1 = b1[nc * 32 + 16 + lane16];
#pragma unroll
    for (int r = 0; r < 4; ++r) {
      int m = w * 16 + quad * 4 + r;
      float v0 = leaky(c0[r] + bv0);
      float v1 = leaky(c1[r] + bv1);
      unsigned short h0 = bf16_rne(v0);
      unsigned short l0 = bf16_rne(v0 - __uint_as_float(((unsigned)h0) << 16));
      unsigned short h1v = bf16_rne(v1);
      unsigned short l1 = bf16_rne(v1 - __uint_as_float(((unsigned)h1v) << 16));
      *(unsigned short*)(h1h + m * 64 + swz64(m, lane16 * 2)) = h0;
      *(unsigned short*)(h1l + m * 64 + swz64(m, lane16 * 2)) = l0;
      *(unsigned short*)(h1h + m * 64 + swz64(m, 32 + lane16 * 2)) = h1v;
      *(unsigned short*)(h1l + m * 64 + swz64(m, 32 + lane16 * 2)) = l1;
    }
    // layer2 A-frags: direct bf16x8 reads (same wave's rows; lgkm-ordered)
    bf16x8 ah = *(const bf16x8*)(h1h + am * 64 + swz64(am, quad * 16));
    bf16x8 al = *(const bf16x8*)(h1l + am * 64 + swz64(am, quad * 16));
#pragma unroll
    for (int t = 0; t < 8; ++t) {
      bf16x8 bh = (t & 1) ? p1h : p0h;
      bf16x8 bl = (t & 1) ? p1l : p0l;
      if (t < 6) {  // refill the slot just consumed with tile t+2
        const char* g = g2 + (t + 2) * 2048;
        if (t & 1) {
          p1h = *(const bf16x8*)(g + L16);
          p1l = *(const bf16x8*)(g + 1024 + L16);
        } else {
          p0h = *(const bf16x8*)(g + L16);
          p0l = *(const bf16x8*)(g + 1024 + L16);
        }
      }
      __builtin_amdgcn_s_setprio(1);
      acc2[t] = MFMA(ah, bh, acc2[t]);
      acc2[t] = MFMA(ah, bl, acc2[t]);
      acc2[t] = MFMA(al, bh, acc2[t]);
      __builtin_amdgcn_s_setprio(0);
    }
  }

  // --- h2 epilogue: leaky + split -> h2 hi/lo planes (wave-private rows) ---
#pragma unroll
  for (int t = 0; t < 8; ++t) {
#pragma unroll
    for (int r = 0; r < 4; ++r) {
      int m = w * 16 + quad * 4 + r;
      float v = leaky(acc2[t][r]);
      unsigned short h = bf16_rne(v);
      unsigned short l = bf16_rne(v - __uint_as_float(((unsigned)h) << 16));
      int off = (t * 16 + lane16) * 2;
      *(unsigned short*)(h2h + m * 256 + swz256(m, off)) = h;
      *(unsigned short*)(h2l + m * 256 + swz256(m, off)) = l;
    }
  }

  // --- layer3: 2 C-tiles (N=32), K=128; pw3 depth-1 register pipeline ---
  bf16x8 m0, m1, m2, m3;
  {
    const char* g = (const char*)pw3;
    m0 = *(const bf16x8*)(g + L16);
    m1 = *(const bf16x8*)(g + 1024 + L16);
    m2 = *(const bf16x8*)(g + 2048 + L16);
    m3 = *(const bf16x8*)(g + 3072 + L16);
  }
  f32x4 d0 = (f32x4){0.f, 0.f, 0.f, 0.f};
  f32x4 d1 = (f32x4){0.f, 0.f, 0.f, 0.f};
#pragma unroll
  for (int kc = 0; kc < 4; ++kc) {
    bf16x8 q0 = m0, q1 = m1, q2 = m2, q3 = m3;
    if (kc < 3) {
      const char* g = (const char*)pw3 + (kc + 1) * 4096;
      m0 = *(const bf16x8*)(g + L16);
      m1 = *(const bf16x8*)(g + 1024 + L16);
      m2 = *(const bf16x8*)(g + 2048 + L16);
      m3 = *(const bf16x8*)(g + 3072 + L16);
    }
    bf16x8 ah = *(const bf16x8*)(h2h + am * 256 + swz256(am, kc * 64 + quad * 16));
    bf16x8 al = *(const bf16x8*)(h2l + am * 256 + swz256(am, kc * 64 + quad * 16));
    __builtin_amdgcn_s_setprio(1);
    d0 = MFMA(ah, q0, d0);
    d1 = MFMA(ah, q2, d1);
    d0 = MFMA(ah, q1, d0);
    d1 = MFMA(ah, q3, d1);
    d0 = MFMA(al, q0, d0);
    d1 = MFMA(al, q2, d1);
    __builtin_amdgcn_s_setprio(0);
  }

  // --- epilogue: residual + fire (fire values pulled via shuffle) ---
  float fr[4];
#pragma unroll
  for (int r = 0; r < 4; ++r) fr[r] = __shfl(fire, quad * 4 + r, 64);
  int gy = ty0 + w;
  int gxq = tx0 + quad * 4;
  float* ob = sout + b * 29 * 4096;
#pragma unroll
  for (int t3 = 0; t3 < 2; ++t3) {
    int c = t3 * 16 + lane16;
    if (c >= 3 && c <= 28) {
      float4 so = *(const float4*)(sb + c * 4096 + gy * 64 + gxq);
      f32x4 d = t3 ? d1 : d0;
      float4 o;
      o.x = fmaf(fr[0], d[0], so.x);
      o.y = fmaf(fr[1], d[1], so.y);
      o.z = fmaf(fr[2], d[2], so.z);
      o.w = fmaf(fr[3], d[3], so.w);
      *(float4*)(ob + c * 4096 + gy * 64 + gxq) = o;
    }
  }
}

// ---------------------------------------------------------------------------
__global__ __launch_bounds__(256) void finalize(const float* __restrict__ s,
                                                float* __restrict__ out) {
  __shared__ float red[256];
  __shared__ float ls[10];
  int b = blockIdx.x, tid = threadIdx.x;
  const float* sb = s + b * 29 * 4096;
  for (int o = 0; o < 10; ++o) {
    const float* ch = sb + (19 + o) * 4096;
    float p = 0.0f;
    for (int i = tid; i < 4096; i += 256) p += ch[i];
    red[tid] = p;
    __syncthreads();
    for (int st = 128; st > 0; st >>= 1) {
      if (tid < st) red[tid] += red[tid + st];
      __syncthreads();
    }
    if (tid == 0) ls[o] = red[0] * (1.0f / 4096.0f);
    __syncthreads();
  }
  if (tid == 0) {
    float m = ls[0];
    for (int o = 1; o < 10; ++o) m = fmaxf(m, ls[o]);
    float e[10], sum = 0.0f;
    for (int o = 0; o < 10; ++o) { e[o] = expf(ls[o] - m); sum += e[o]; }
    for (int o = 0; o < 10; ++o) out[b * 10 + o] = e[o] / sum;
  }
}

// ---------------------------------------------------------------------------
extern "C" void kernel_launch(void* const* d_in, const int* in_sizes, int n_in,
                              void* d_out, int out_size, void* d_ws, size_t ws_size,
                              hipStream_t stream) {
  const float* x  = (const float*)d_in[0];
  const float* w1 = (const float*)d_in[1];
  const float* b1 = (const float*)d_in[2];
  const float* w2 = (const float*)d_in[3];
  const float* w3 = (const float*)d_in[4];
  const int STEPS = 20;  // setup_inputs() fixes steps=20

  const size_t STATE = (size_t)16 * 29 * 4096;
  float* ws = (float*)d_ws;
  float* s0 = ws;
  float* s1 = ws + STATE;
  unsigned short* pw1 = (unsigned short*)(ws + 2 * STATE);  // 96*512 shorts
  unsigned short* pw2 = pw1 + 96 * 512;                      // 128*512
  unsigned short* pw3 = pw2 + 128 * 512;                     // 16*512
  (void)ws_size; (void)n_in; (void)in_sizes; (void)out_size;

  prep_weights<<<256, 256, 0, stream>>>(w1, w2, w3, pw1, pw2, pw3);

  U2 hk = tf2x32(0u, 42u, 0u, 10000u);  // fold_in(key(42), 10000)
  init_state<<<(16 * 29 * 4096 + 255) / 256, 256, 0, stream>>>(x, s0, s1, hk.a, hk.b);

  for (int s = 0; s < STEPS; ++s) {
    U2 fk = tf2x32(0u, 42u, 0u, (unsigned)s);  // fold_in(key(42), step)
    float tval = (float)s / 100.0f;
    const float* in = (s & 1) ? s1 : s0;
    float* out = (s & 1) ? s0 : s1;
    dim3 grid(4, 16, 16);
    nca_step<<<grid, 256, 0, stream>>>(in, out, pw1, b1, pw2, pw3, tval, fk.a, fk.b);
  }
  finalize<<<16, 256, 0, stream>>>(s0, (float*)d_out);
}

// Round 2
// 922.465 us; speedup vs baseline: 1.0679x; 1.0653x over previous
//
#include <hip/hip_runtime.h>

// ---------------------------------------------------------------------------
// ClassificationNCA — Round 6: VALU diet + halo load unroll.
// R5 structure kept (register-pipelined weight tiles, setprio, 40960 B LDS,
// 2 barriers/step). New: all bf16 hi/lo splits via v_cvt_pk_bf16_f32 inline
// asm (RNE == bf16_rne -> bit-identical), leaky via fmaxf(v, .01v) (exact),
// halo load fully unrolled with register staging (13 loads in flight instead
// of 13 serial vmcnt(0) round-trips).
// ---------------------------------------------------------------------------

#define ROTL32(x, d) (((x) << (d)) | ((x) >> (32 - (d))))

struct U2 { unsigned a, b; };

__host__ __device__ inline U2 tf2x32(unsigned k0, unsigned k1, unsigned c0, unsigned c1) {
  unsigned ks2 = k0 ^ k1 ^ 0x1BD11BDAu;
  unsigned x0 = c0 + k0;
  unsigned x1 = c1 + k1;
#define TF_ROUND4(r0, r1, r2, r3)                                              \
  x0 += x1; x1 = ROTL32(x1, r0); x1 ^= x0;                                     \
  x0 += x1; x1 = ROTL32(x1, r1); x1 ^= x0;                                     \
  x0 += x1; x1 = ROTL32(x1, r2); x1 ^= x0;                                     \
  x0 += x1; x1 = ROTL32(x1, r3); x1 ^= x0;
  TF_ROUND4(13, 15, 26, 6)
  x0 += k1;  x1 += ks2 + 1u;
  TF_ROUND4(17, 29, 16, 24)
  x0 += ks2; x1 += k0 + 2u;
  TF_ROUND4(13, 15, 26, 6)
  x0 += k0;  x1 += k1 + 3u;
  TF_ROUND4(17, 29, 16, 24)
  x0 += k1;  x1 += ks2 + 4u;
  TF_ROUND4(13, 15, 26, 6)
  x0 += ks2; x1 += k0 + 5u;
#undef TF_ROUND4
  U2 r; r.a = x0; r.b = x1; return r;
}

__device__ inline float erfinv_xla(float x) {
  float w = -log1pf(-x * x);
  float p;
  if (w < 5.0f) {
    w -= 2.5f;
    p = 2.81022636e-08f;
    p = fmaf(p, w, 3.43273939e-07f);
    p = fmaf(p, w, -3.5233877e-06f);
    p = fmaf(p, w, -4.39150654e-06f);
    p = fmaf(p, w, 0.00021858087f);
    p = fmaf(p, w, -0.00125372503f);
    p = fmaf(p, w, -0.00417768164f);
    p = fmaf(p, w, 0.246640727f);
    p = fmaf(p, w, 1.50140941f);
  } else {
    w = sqrtf(w) - 3.0f;
    p = -0.000200214257f;
    p = fmaf(p, w, 0.000100950558f);
    p = fmaf(p, w, 0.00134934322f);
    p = fmaf(p, w, -0.00367342844f);
    p = fmaf(p, w, 0.00573950773f);
    p = fmaf(p, w, -0.0076224613f);
    p = fmaf(p, w, 0.00943887047f);
    p = fmaf(p, w, 1.00167406f);
    p = fmaf(p, w, 2.83297682f);
  }
  return p * x;
}

// Exact rewrite of (v>=0 ? v : .01v): for v<0, .01v > v; for v>=0, .01v <= v.
__device__ inline float leaky(float v) { return fmaxf(v, 0.01f * v); }

typedef __attribute__((ext_vector_type(8))) short bf16x8;
typedef __attribute__((ext_vector_type(4))) float f32x4;
typedef __attribute__((ext_vector_type(4))) unsigned int u32x4;

__host__ __device__ inline unsigned short bf16_rne(float x) {
  unsigned u = __float_as_uint(x);
  return (unsigned short)((u + 0x7FFFu + ((u >> 16) & 1u)) >> 16);
}

// v_cvt_pk_bf16_f32: dst[15:0]=bf16_rne(a), dst[31:16]=bf16_rne(b). 1 instr
// for 2 conversions (no builtin on gfx950 -> inline asm).
__device__ inline unsigned cvtpk(float a, float b) {
  unsigned r;
  asm("v_cvt_pk_bf16_f32 %0, %1, %2" : "=v"(r) : "v"(a), "v"(b));
  return r;
}

union Frag8 { u32x4 u; bf16x8 v; };

__device__ inline void split8(const float v[8], bf16x8& hi, bf16x8& lo) {
  Frag8 H, L;
#pragma unroll
  for (int j = 0; j < 8; j += 2) {
    unsigned p = cvtpk(v[j], v[j + 1]);
    H.u[j >> 1] = p;
    float r0 = v[j]     - __uint_as_float(p << 16);
    float r1 = v[j + 1] - __uint_as_float(p & 0xFFFF0000u);
    L.u[j >> 1] = cvtpk(r0, r1);
  }
  hi = H.v;
  lo = L.v;
}

// XOR swizzles: 16B groups; 4-group window (64B rows) / 8-group window (256B).
__device__ inline int swz64(int m, int off) {
  int g = (off >> 4) ^ (m & 3);
  return (g << 4) | (off & 15);
}
__device__ inline int swz256(int m, int off) {
  int g = off >> 4;
  g = (g & ~7) | ((g ^ (m & 7)) & 7);
  return (g << 4) | (off & 15);
}

#define MFMA(a, b, c) __builtin_amdgcn_mfma_f32_16x16x32_bf16((a), (b), (c), 0, 0, 0)

// ---------------------------------------------------------------------------
// Weight prep: fragment-major packed B-tiles (1 KB/tile), as in R3/R4.
// ---------------------------------------------------------------------------
__global__ void prep_weights(const float* __restrict__ w1, const float* __restrict__ w2,
                             const float* __restrict__ w3,
                             unsigned short* __restrict__ pw1,
                             unsigned short* __restrict__ pw2,
                             unsigned short* __restrict__ pw3) {
  int i = blockIdx.x * 256 + threadIdx.x;
  int e = i & 511, L = e >> 3, j = e & 7;
  int kq = (L >> 4) * 8 + j;   // k within 32-chunk
  int ln = L & 15;             // n within 16-tile
  if (i < 96 * 512) {          // pw1: [nc(8)][kc(3)][f(4)]
    int tile = i >> 9;
    int f = tile & 3, kc = (tile >> 2) % 3, nc = tile / 12;
    int n = nc * 32 + (f >> 1) * 16 + ln;
    int src;
    if (kc == 0)      src = (kq < 29) ? kq : -1;
    else if (kc == 1) src = (kq < 29) ? 29 + kq : ((kq == 29) ? 87 : -1);
    else              src = (kq < 29) ? 58 + kq : -1;
    float v = (src >= 0) ? w1[n * 88 + src] : 0.0f;
    unsigned short h = bf16_rne(v);
    pw1[i] = (f & 1) ? bf16_rne(v - __uint_as_float(((unsigned)h) << 16)) : h;
  }
  if (i < 128 * 512) {         // pw2: [nc(8)][t(8)][h,l]
    int tile = i >> 9;
    int hl = tile & 1, t = (tile >> 1) & 7, nc = tile >> 4;
    int n = t * 16 + ln;
    int k = nc * 32 + kq;
    float v = w2[n * 256 + k];
    unsigned short h = bf16_rne(v);
    pw2[i] = hl ? bf16_rne(v - __uint_as_float(((unsigned)h) << 16)) : h;
  }
  if (i < 16 * 512) {          // pw3: [kc(4)][f(4)]
    int tile = i >> 9;
    int f = tile & 3, kc = tile >> 2;
    int n = (f >> 1) * 16 + ln;
    int k = kc * 32 + kq;
    float v = (n < 29) ? w3[n * 128 + k] : 0.0f;
    unsigned short h = bf16_rne(v);
    pw3[i] = (f & 1) ? bf16_rne(v - __uint_as_float(((unsigned)h) << 16)) : h;
  }
}

// ---------------------------------------------------------------------------
__global__ void init_state(const float* __restrict__ x, float* __restrict__ s0,
                           float* __restrict__ s1, unsigned hk0, unsigned hk1) {
  int idx = blockIdx.x * 256 + threadIdx.x;
  if (idx >= 16 * 29 * 4096) return;
  int pix = idx & 4095;
  int c = (idx >> 12) % 29;
  int b = idx / (4096 * 29);
  float v;
  if (c < 3) {
    v = x[(b * 3 + c) * 4096 + pix];
    s1[idx] = v;
  } else if (c < 19) {
    int ch = c - 3;
    int i = (b * 16 + ch) * 4096 + pix;
    const int half = 131072;
    unsigned bits;
    if (i < half) bits = tf2x32(hk0, hk1, (unsigned)i, (unsigned)(i + half)).a;
    else          bits = tf2x32(hk0, hk1, (unsigned)(i - half), (unsigned)i).b;
    float f = __uint_as_float((bits >> 9) | 0x3F800000u) - 1.0f;
    const float lo = -0x1.fffffep-1f;
    float u = fmaxf(lo, fmaf(f, 2.0f, lo));
    v = fmaf(0.225f, 1.41421356237f * erfinv_xla(u), 0.5f);
  } else {
    v = 0.0f;
  }
  s0[idx] = v;
}

// ---------------------------------------------------------------------------
// One NCA step. LDS map (bytes), total 40960:
//   [0     ..  4096)  h1h  ushort[64][32], row 64 B, swz64
//   [4096  ..  8192)  h1l  ushort[64][32]
//   [8192  .. 24576)  h2h  ushort[64][128], row 256 B, swz256
//   [24576 .. 40960)  h2l  ushort[64][128]
//   sS halo float[29][stride 109] overlays [8192, 20836); dump slot 3160.
// ---------------------------------------------------------------------------
__global__ __launch_bounds__(256, 4) void nca_step(
    const float* __restrict__ sin_, float* __restrict__ sout,
    const unsigned short* __restrict__ pw1, const float* __restrict__ b1,
    const unsigned short* __restrict__ pw2, const unsigned short* __restrict__ pw3,
    float tval, unsigned fk0, unsigned fk1) {
  __shared__ __align__(16) char lds[40960];
  char* h1h = lds;
  char* h1l = lds + 4096;
  char* h2h = lds + 8192;
  char* h2l = lds + 24576;
  float* sS = (float*)(lds + 8192);   // channel stride 109 floats (bank-spread)

  const int tid = threadIdx.x;
  const int w = tid >> 6;
  const int L = tid & 63;
  const int lane16 = L & 15;
  const int quad = L >> 4;
  const int b = blockIdx.z;
  const int ty0 = blockIdx.y * 4;
  const int tx0 = blockIdx.x * 16;
  const float* sb = sin_ + b * 29 * 4096;

  // --- P1: halo load (29 ch x 6 rows x 18 cols, zero-padded), fully unrolled
  //     register staging: all 13 global loads in flight, then 13 ds_writes.
  {
    float hv[13];
    int hix[13];
#pragma unroll
    for (int it = 0; it < 13; ++it) {
      int l = tid + it * 256;
      int c = l / 108;
      int rem = l - c * 108;
      int r = rem / 18;
      int x = rem - r * 18;
      int gy = ty0 - 1 + r, gx = tx0 - 1 + x;
      bool in = (l < 29 * 108);
      float v = 0.0f;
      if (in && (unsigned)gy < 64u && (unsigned)gx < 64u)
        v = sb[c * 4096 + gy * 64 + gx];
      hv[it] = v;
      hix[it] = in ? (c * 109 + r * 18 + x) : 3160;
    }
#pragma unroll
    for (int it = 0; it < 13; ++it) sS[hix[it]] = hv[it];
  }
  __syncthreads();

  // --- A1 fragments directly from halo (permuted K: ps | px,t | py) ---
  const int am = w * 16 + lane16;
  bf16x8 a1h[3], a1l[3];
  {
    float vps[8], vpx[8], vpy[8];
#pragma unroll
    for (int j = 0; j < 8; ++j) {
      int c = quad * 8 + j;
      int cc = (c < 29) ? c : 0;
      const float* S = sS + cc * 109 + (w + 1) * 18 + (lane16 + 1);
      float m00 = S[-19], m01 = S[-18], m02 = S[-17];
      float m10 = S[-1],  m11 = S[0],   m12 = S[1];
      float m20 = S[17],  m21 = S[18],  m22 = S[19];
      bool valid = (c < 29);
      vps[j] = valid ? m11 : 0.0f;
      float px = ((m02 - m00) + 2.0f * (m12 - m10) + (m22 - m20)) * 0.125f;
      float py = ((m20 + 2.0f * m21 + m22) - (m00 + 2.0f * m01 + m02)) * 0.125f;
      vpx[j] = valid ? px : ((c == 29) ? tval : 0.0f);
      vpy[j] = valid ? py : 0.0f;
    }
    split8(vps, a1h[0], a1l[0]);
    split8(vpx, a1h[1], a1l[1]);
    split8(vpy, a1h[2], a1l[2]);
  }
  __syncthreads();  // sS dead -> h2 region reusable

  const int L16 = L * 16;

  // --- prologue: issue pw1[nc=0,kc=0] tile loads (depth-1 pipeline seed) ---
  bf16x8 n1a, n1b, n1c, n1d;
  {
    const char* g = (const char*)pw1;
    n1a = *(const bf16x8*)(g + L16);
    n1b = *(const bf16x8*)(g + 1024 + L16);
    n1c = *(const bf16x8*)(g + 2048 + L16);
    n1d = *(const bf16x8*)(g + 3072 + L16);
  }

  // --- fire mask (pure VALU; fills prologue load shadow) ---
  float fire;
  {
    int i = b * 4096 + (ty0 + w) * 64 + (tx0 + lane16);
    unsigned bits;
    if (i < 32768) bits = tf2x32(fk0, fk1, (unsigned)i, (unsigned)(i + 32768)).a;
    else           bits = tf2x32(fk0, fk1, (unsigned)(i - 32768), (unsigned)i).b;
    fire = (bits & 0x80000000u) ? 0.0f : 1.0f;
  }

  // --- fused layer1 -> layer2 over 8 n-chunks of 32 ---
  f32x4 acc2[8];
#pragma unroll
  for (int t = 0; t < 8; ++t) acc2[t] = (f32x4){0.f, 0.f, 0.f, 0.f};

#pragma unroll 1
  for (int nc = 0; nc < 8; ++nc) {
    f32x4 c0 = (f32x4){0.f, 0.f, 0.f, 0.f};
    f32x4 c1 = (f32x4){0.f, 0.f, 0.f, 0.f};
#pragma unroll
    for (int kc = 0; kc < 3; ++kc) {
      // consume the preloaded tile; issue the next one first.
      bf16x8 w1a = n1a, w1b = n1b, w1cc = n1c, w1d = n1d;
      {
        // kc<2: next kc of this nc.  kc==2: kc=0 of the NEXT nc.
        const int nt = (kc < 2) ? (nc * 3 + kc + 1) : (((nc + 1) & 7) * 3);
        const char* g = (const char*)pw1 + nt * 4096;
        n1a = *(const bf16x8*)(g + L16);
        n1b = *(const bf16x8*)(g + 1024 + L16);
        n1c = *(const bf16x8*)(g + 2048 + L16);
        n1d = *(const bf16x8*)(g + 3072 + L16);
      }
      __builtin_amdgcn_s_setprio(1);
      // c0/c1 chains interleaved; per-accumulator MFMA order unchanged.
      c0 = MFMA(a1h[kc], w1a, c0);
      c1 = MFMA(a1h[kc], w1cc, c1);
      c0 = MFMA(a1h[kc], w1b, c0);
      c1 = MFMA(a1h[kc], w1d, c1);
      c0 = MFMA(a1l[kc], w1a, c0);
      c1 = MFMA(a1l[kc], w1cc, c1);
      __builtin_amdgcn_s_setprio(0);
    }

    // pw2 pipeline (depth 2): issue t=0,1 tiles BEFORE the h1 epilogue.
    const char* g2 = (const char*)pw2 + nc * 16384;
    bf16x8 p0h = *(const bf16x8*)(g2 + L16);
    bf16x8 p0l = *(const bf16x8*)(g2 + 1024 + L16);
    bf16x8 p1h = *(const bf16x8*)(g2 + 2048 + L16);
    bf16x8 p1l = *(const bf16x8*)(g2 + 3072 + L16);

    // bias + leaky + SPLIT -> h1 hi/lo planes (wave-private rows).
    // cvt_pk packs (v0,v1) -> one u32 (lo16 = v0, hi16 = v1).
    float bv0 = b1[nc * 32 + lane16];
    float bv1 = b1[nc * 32 + 16 + lane16];
#pragma unroll
    for (int r = 0; r < 4; ++r) {
      int m = w * 16 + quad * 4 + r;
      float v0 = leaky(c0[r] + bv0);
      float v1 = leaky(c1[r] + bv1);
      unsigned ph = cvtpk(v0, v1);
      float r0 = v0 - __uint_as_float(ph << 16);
      float r1 = v1 - __uint_as_float(ph & 0xFFFF0000u);
      unsigned pl = cvtpk(r0, r1);
      *(unsigned short*)(h1h + m * 64 + swz64(m, lane16 * 2)) = (unsigned short)ph;
      *(unsigned short*)(h1h + m * 64 + swz64(m, 32 + lane16 * 2)) = (unsigned short)(ph >> 16);
      *(unsigned short*)(h1l + m * 64 + swz64(m, lane16 * 2)) = (unsigned short)pl;
      *(unsigned short*)(h1l + m * 64 + swz64(m, 32 + lane16 * 2)) = (unsigned short)(pl >> 16);
    }
    // layer2 A-frags: direct bf16x8 reads (same wave's rows; lgkm-ordered)
    bf16x8 ah = *(const bf16x8*)(h1h + am * 64 + swz64(am, quad * 16));
    bf16x8 al = *(const bf16x8*)(h1l + am * 64 + swz64(am, quad * 16));
#pragma unroll
    for (int t = 0; t < 8; ++t) {
      bf16x8 bh = (t & 1) ? p1h : p0h;
      bf16x8 bl = (t & 1) ? p1l : p0l;
      if (t < 6) {  // refill the slot just consumed with tile t+2
        const char* g = g2 + (t + 2) * 2048;
        if (t & 1) {
          p1h = *(const bf16x8*)(g + L16);
          p1l = *(const bf16x8*)(g + 1024 + L16);
        } else {
          p0h = *(const bf16x8*)(g + L16);
          p0l = *(const bf16x8*)(g + 1024 + L16);
        }
      }
      __builtin_amdgcn_s_setprio(1);
      acc2[t] = MFMA(ah, bh, acc2[t]);
      acc2[t] = MFMA(ah, bl, acc2[t]);
      acc2[t] = MFMA(al, bh, acc2[t]);
      __builtin_amdgcn_s_setprio(0);
    }
  }

  // --- h2 epilogue: leaky + split -> h2 hi/lo planes (pairs across t) ---
#pragma unroll
  for (int t = 0; t < 8; t += 2) {
#pragma unroll
    for (int r = 0; r < 4; ++r) {
      int m = w * 16 + quad * 4 + r;
      float va = leaky(acc2[t][r]);
      float vb = leaky(acc2[t + 1][r]);
      unsigned ph = cvtpk(va, vb);
      float ra = va - __uint_as_float(ph << 16);
      float rb = vb - __uint_as_float(ph & 0xFFFF0000u);
      unsigned pl = cvtpk(ra, rb);
      int offa = (t * 16 + lane16) * 2;
      int offb = ((t + 1) * 16 + lane16) * 2;
      *(unsigned short*)(h2h + m * 256 + swz256(m, offa)) = (unsigned short)ph;
      *(unsigned short*)(h2h + m * 256 + swz256(m, offb)) = (unsigned short)(ph >> 16);
      *(unsigned short*)(h2l + m * 256 + swz256(m, offa)) = (unsigned short)pl;
      *(unsigned short*)(h2l + m * 256 + swz256(m, offb)) = (unsigned short)(pl >> 16);
    }
  }

  // --- layer3: 2 C-tiles (N=32), K=128; pw3 depth-1 register pipeline ---
  bf16x8 m0, m1, m2, m3;
  {
    const char* g = (const char*)pw3;
    m0 = *(const bf16x8*)(g + L16);
    m1 = *(const bf16x8*)(g + 1024 + L16);
    m2 = *(const bf16x8*)(g + 2048 + L16);
    m3 = *(const bf16x8*)(g + 3072 + L16);
  }
  f32x4 d0 = (f32x4){0.f, 0.f, 0.f, 0.f};
  f32x4 d1 = (f32x4){0.f, 0.f, 0.f, 0.f};
#pragma unroll
  for (int kc = 0; kc < 4; ++kc) {
    bf16x8 q0 = m0, q1 = m1, q2 = m2, q3 = m3;
    if (kc < 3) {
      const char* g = (const char*)pw3 + (kc + 1) * 4096;
      m0 = *(const bf16x8*)(g + L16);
      m1 = *(const bf16x8*)(g + 1024 + L16);
      m2 = *(const bf16x8*)(g + 2048 + L16);
      m3 = *(const bf16x8*)(g + 3072 + L16);
    }
    bf16x8 ah = *(const bf16x8*)(h2h + am * 256 + swz256(am, kc * 64 + quad * 16));
    bf16x8 al = *(const bf16x8*)(h2l + am * 256 + swz256(am, kc * 64 + quad * 16));
    __builtin_amdgcn_s_setprio(1);
    d0 = MFMA(ah, q0, d0);
    d1 = MFMA(ah, q2, d1);
    d0 = MFMA(ah, q1, d0);
    d1 = MFMA(ah, q3, d1);
    d0 = MFMA(al, q0, d0);
    d1 = MFMA(al, q2, d1);
    __builtin_amdgcn_s_setprio(0);
  }

  // --- epilogue: residual + fire (fire values pulled via shuffle) ---
  float fr[4];
#pragma unroll
  for (int r = 0; r < 4; ++r) fr[r] = __shfl(fire, quad * 4 + r, 64);
  int gy = ty0 + w;
  int gxq = tx0 + quad * 4;
  float* ob = sout + b * 29 * 4096;
#pragma unroll
  for (int t3 = 0; t3 < 2; ++t3) {
    int c = t3 * 16 + lane16;
    if (c >= 3 && c <= 28) {
      float4 so = *(const float4*)(sb + c * 4096 + gy * 64 + gxq);
      f32x4 d = t3 ? d1 : d0;
      float4 o;
      o.x = fmaf(fr[0], d[0], so.x);
      o.y = fmaf(fr[1], d[1], so.y);
      o.z = fmaf(fr[2], d[2], so.z);
      o.w = fmaf(fr[3], d[3], so.w);
      *(float4*)(ob + c * 4096 + gy * 64 + gxq) = o;
    }
  }
}

// ---------------------------------------------------------------------------
__global__ __launch_bounds__(256) void finalize(const float* __restrict__ s,
                                                float* __restrict__ out) {
  __shared__ float red[256];
  __shared__ float ls[10];
  int b = blockIdx.x, tid = threadIdx.x;
  const float* sb = s + b * 29 * 4096;
  for (int o = 0; o < 10; ++o) {
    const float* ch = sb + (19 + o) * 4096;
    float p = 0.0f;
    for (int i = tid; i < 4096; i += 256) p += ch[i];
    red[tid] = p;
    __syncthreads();
    for (int st = 128; st > 0; st >>= 1) {
      if (tid < st) red[tid] += red[tid + st];
      __syncthreads();
    }
    if (tid == 0) ls[o] = red[0] * (1.0f / 4096.0f);
    __syncthreads();
  }
  if (tid == 0) {
    float m = ls[0];
    for (int o = 1; o < 10; ++o) m = fmaxf(m, ls[o]);
    float e[10], sum = 0.0f;
    for (int o = 0; o < 10; ++o) { e[o] = expf(ls[o] - m); sum += e[o]; }
    for (int o = 0; o < 10; ++o) out[b * 10 + o] = e[o] / sum;
  }
}

// ---------------------------------------------------------------------------
extern "C" void kernel_launch(void* const* d_in, const int* in_sizes, int n_in,
                              void* d_out, int out_size, void* d_ws, size_t ws_size,
                              hipStream_t stream) {
  const float* x  = (const float*)d_in[0];
  const float* w1 = (const float*)d_in[1];
  const float* b1 = (const float*)d_in[2];
  const float* w2 = (const float*)d_in[3];
  const float* w3 = (const float*)d_in[4];
  const int STEPS = 20;  // setup_inputs() fixes steps=20

  const size_t STATE = (size_t)16 * 29 * 4096;
  float* ws = (float*)d_ws;
  float* s0 = ws;
  float* s1 = ws + STATE;
  unsigned short* pw1 = (unsigned short*)(ws + 2 * STATE);  // 96*512 shorts
  unsigned short* pw2 = pw1 + 96 * 512;                      // 128*512
  unsigned short* pw3 = pw2 + 128 * 512;                     // 16*512
  (void)ws_size; (void)n_in; (void)in_sizes; (void)out_size;

  prep_weights<<<256, 256, 0, stream>>>(w1, w2, w3, pw1, pw2, pw3);

  U2 hk = tf2x32(0u, 42u, 0u, 10000u);  // fold_in(key(42), 10000)
  init_state<<<(16 * 29 * 4096 + 255) / 256, 256, 0, stream>>>(x, s0, s1, hk.a, hk.b);

  for (int s = 0; s < STEPS; ++s) {
    U2 fk = tf2x32(0u, 42u, 0u, (unsigned)s);  // fold_in(key(42), step)
    float tval = (float)s / 100.0f;
    const float* in = (s & 1) ? s1 : s0;
    float* out = (s & 1) ? s0 : s1;
    dim3 grid(4, 16, 16);
    nca_step<<<grid, 256, 0, stream>>>(in, out, pw1, b1, pw2, pw3, tval, fk.a, fk.b);
  }
  finalize<<<16, 256, 0, stream>>>(s0, (float*)d_out);
}

// Round 3
// 735.180 us; speedup vs baseline: 1.3400x; 1.2547x over previous
//
#include <hip/hip_runtime.h>

// ---------------------------------------------------------------------------
// ClassificationNCA — Round 7: M=32 per wave (128-pixel blocks).
// Each wave computes TWO 16-row MFMA tiles sharing ONE weight-fragment
// stream -> per-CU weight VMEM bytes halve (the R6 bottleneck: ~64B/cyc/CU
// L1-return bus at ~60% busy). Tile = 8 rows x 16 cols; grid 512 blocks;
// LDS 81920 B = exactly 2 blocks/CU (8 waves/CU). Per-pixel numerics,
// MFMA chain order, threefry, epilogue identical -> bit-identical output.
// ---------------------------------------------------------------------------

#define ROTL32(x, d) (((x) << (d)) | ((x) >> (32 - (d))))

struct U2 { unsigned a, b; };

__host__ __device__ inline U2 tf2x32(unsigned k0, unsigned k1, unsigned c0, unsigned c1) {
  unsigned ks2 = k0 ^ k1 ^ 0x1BD11BDAu;
  unsigned x0 = c0 + k0;
  unsigned x1 = c1 + k1;
#define TF_ROUND4(r0, r1, r2, r3)                                              \
  x0 += x1; x1 = ROTL32(x1, r0); x1 ^= x0;                                     \
  x0 += x1; x1 = ROTL32(x1, r1); x1 ^= x0;                                     \
  x0 += x1; x1 = ROTL32(x1, r2); x1 ^= x0;                                     \
  x0 += x1; x1 = ROTL32(x1, r3); x1 ^= x0;
  TF_ROUND4(13, 15, 26, 6)
  x0 += k1;  x1 += ks2 + 1u;
  TF_ROUND4(17, 29, 16, 24)
  x0 += ks2; x1 += k0 + 2u;
  TF_ROUND4(13, 15, 26, 6)
  x0 += k0;  x1 += k1 + 3u;
  TF_ROUND4(17, 29, 16, 24)
  x0 += k1;  x1 += ks2 + 4u;
  TF_ROUND4(13, 15, 26, 6)
  x0 += ks2; x1 += k0 + 5u;
#undef TF_ROUND4
  U2 r; r.a = x0; r.b = x1; return r;
}

__device__ inline float erfinv_xla(float x) {
  float w = -log1pf(-x * x);
  float p;
  if (w < 5.0f) {
    w -= 2.5f;
    p = 2.81022636e-08f;
    p = fmaf(p, w, 3.43273939e-07f);
    p = fmaf(p, w, -3.5233877e-06f);
    p = fmaf(p, w, -4.39150654e-06f);
    p = fmaf(p, w, 0.00021858087f);
    p = fmaf(p, w, -0.00125372503f);
    p = fmaf(p, w, -0.00417768164f);
    p = fmaf(p, w, 0.246640727f);
    p = fmaf(p, w, 1.50140941f);
  } else {
    w = sqrtf(w) - 3.0f;
    p = -0.000200214257f;
    p = fmaf(p, w, 0.000100950558f);
    p = fmaf(p, w, 0.00134934322f);
    p = fmaf(p, w, -0.00367342844f);
    p = fmaf(p, w, 0.00573950773f);
    p = fmaf(p, w, -0.0076224613f);
    p = fmaf(p, w, 0.00943887047f);
    p = fmaf(p, w, 1.00167406f);
    p = fmaf(p, w, 2.83297682f);
  }
  return p * x;
}

// Exact rewrite of (v>=0 ? v : .01v).
__device__ inline float leaky(float v) { return fmaxf(v, 0.01f * v); }

typedef __attribute__((ext_vector_type(8))) short bf16x8;
typedef __attribute__((ext_vector_type(4))) float f32x4;
typedef __attribute__((ext_vector_type(4))) unsigned int u32x4;

__host__ __device__ inline unsigned short bf16_rne(float x) {
  unsigned u = __float_as_uint(x);
  return (unsigned short)((u + 0x7FFFu + ((u >> 16) & 1u)) >> 16);
}

// v_cvt_pk_bf16_f32: dst[15:0]=bf16_rne(a), dst[31:16]=bf16_rne(b).
__device__ inline unsigned cvtpk(float a, float b) {
  unsigned r;
  asm("v_cvt_pk_bf16_f32 %0, %1, %2" : "=v"(r) : "v"(a), "v"(b));
  return r;
}

union Frag8 { u32x4 u; bf16x8 v; };

__device__ inline void split8(const float v[8], bf16x8& hi, bf16x8& lo) {
  Frag8 H, L;
#pragma unroll
  for (int j = 0; j < 8; j += 2) {
    unsigned p = cvtpk(v[j], v[j + 1]);
    H.u[j >> 1] = p;
    float r0 = v[j]     - __uint_as_float(p << 16);
    float r1 = v[j + 1] - __uint_as_float(p & 0xFFFF0000u);
    L.u[j >> 1] = cvtpk(r0, r1);
  }
  hi = H.v;
  lo = L.v;
}

// XOR swizzles: 16B groups; 4-group window (64B rows) / 8-group window (256B).
__device__ inline int swz64(int m, int off) {
  int g = (off >> 4) ^ (m & 3);
  return (g << 4) | (off & 15);
}
__device__ inline int swz256(int m, int off) {
  int g = off >> 4;
  g = (g & ~7) | ((g ^ (m & 7)) & 7);
  return (g << 4) | (off & 15);
}

#define MFMA(a, b, c) __builtin_amdgcn_mfma_f32_16x16x32_bf16((a), (b), (c), 0, 0, 0)

// ---------------------------------------------------------------------------
// Weight prep: fragment-major packed B-tiles (1 KB/tile), unchanged.
// ---------------------------------------------------------------------------
__global__ void prep_weights(const float* __restrict__ w1, const float* __restrict__ w2,
                             const float* __restrict__ w3,
                             unsigned short* __restrict__ pw1,
                             unsigned short* __restrict__ pw2,
                             unsigned short* __restrict__ pw3) {
  int i = blockIdx.x * 256 + threadIdx.x;
  int e = i & 511, L = e >> 3, j = e & 7;
  int kq = (L >> 4) * 8 + j;   // k within 32-chunk
  int ln = L & 15;             // n within 16-tile
  if (i < 96 * 512) {          // pw1: [nc(8)][kc(3)][f(4)]
    int tile = i >> 9;
    int f = tile & 3, kc = (tile >> 2) % 3, nc = tile / 12;
    int n = nc * 32 + (f >> 1) * 16 + ln;
    int src;
    if (kc == 0)      src = (kq < 29) ? kq : -1;
    else if (kc == 1) src = (kq < 29) ? 29 + kq : ((kq == 29) ? 87 : -1);
    else              src = (kq < 29) ? 58 + kq : -1;
    float v = (src >= 0) ? w1[n * 88 + src] : 0.0f;
    unsigned short h = bf16_rne(v);
    pw1[i] = (f & 1) ? bf16_rne(v - __uint_as_float(((unsigned)h) << 16)) : h;
  }
  if (i < 128 * 512) {         // pw2: [nc(8)][t(8)][h,l]
    int tile = i >> 9;
    int hl = tile & 1, t = (tile >> 1) & 7, nc = tile >> 4;
    int n = t * 16 + ln;
    int k = nc * 32 + kq;
    float v = w2[n * 256 + k];
    unsigned short h = bf16_rne(v);
    pw2[i] = hl ? bf16_rne(v - __uint_as_float(((unsigned)h) << 16)) : h;
  }
  if (i < 16 * 512) {          // pw3: [kc(4)][f(4)]
    int tile = i >> 9;
    int f = tile & 3, kc = tile >> 2;
    int n = (f >> 1) * 16 + ln;
    int k = kc * 32 + kq;
    float v = (n < 29) ? w3[n * 128 + k] : 0.0f;
    unsigned short h = bf16_rne(v);
    pw3[i] = (f & 1) ? bf16_rne(v - __uint_as_float(((unsigned)h) << 16)) : h;
  }
}

// ---------------------------------------------------------------------------
__global__ void init_state(const float* __restrict__ x, float* __restrict__ s0,
                           float* __restrict__ s1, unsigned hk0, unsigned hk1) {
  int idx = blockIdx.x * 256 + threadIdx.x;
  if (idx >= 16 * 29 * 4096) return;
  int pix = idx & 4095;
  int c = (idx >> 12) % 29;
  int b = idx / (4096 * 29);
  float v;
  if (c < 3) {
    v = x[(b * 3 + c) * 4096 + pix];
    s1[idx] = v;
  } else if (c < 19) {
    int ch = c - 3;
    int i = (b * 16 + ch) * 4096 + pix;
    const int half = 131072;
    unsigned bits;
    if (i < half) bits = tf2x32(hk0, hk1, (unsigned)i, (unsigned)(i + half)).a;
    else          bits = tf2x32(hk0, hk1, (unsigned)(i - half), (unsigned)i).b;
    float f = __uint_as_float((bits >> 9) | 0x3F800000u) - 1.0f;
    const float lo = -0x1.fffffep-1f;
    float u = fmaxf(lo, fmaf(f, 2.0f, lo));
    v = fmaf(0.225f, 1.41421356237f * erfinv_xla(u), 0.5f);
  } else {
    v = 0.0f;
  }
  s0[idx] = v;
}

// ---------------------------------------------------------------------------
// One NCA step, 128-pixel blocks (8 rows x 16 cols). LDS map (bytes), 81920:
//   [0     ..  8192)  h1h  ushort[128][32], row 64 B, swz64
//   [8192  .. 16384)  h1l  ushort[128][32]
//   [16384 .. 49152)  h2h  ushort[128][128], row 256 B, swz256
//   [49152 .. 81920)  h2l  ushort[128][128]
//   sS halo float[29][stride 181] (10 rows x 18 cols) overlays h2h region
//   (20996 B < 32768; dead before first h2 write). Dump slot 5249.
// Wave w owns pixel rows y = {2w, 2w+1} (M rows [w*32, w*32+32)).
// ---------------------------------------------------------------------------
__global__ __launch_bounds__(256, 2) void nca_step(
    const float* __restrict__ sin_, float* __restrict__ sout,
    const unsigned short* __restrict__ pw1, const float* __restrict__ b1,
    const unsigned short* __restrict__ pw2, const unsigned short* __restrict__ pw3,
    float tval, unsigned fk0, unsigned fk1) {
  __shared__ __align__(16) char lds[81920];
  char* h1h = lds;
  char* h1l = lds + 8192;
  char* h2h = lds + 16384;
  char* h2l = lds + 49152;
  float* sS = (float*)(lds + 16384);   // 29 ch x 181 floats

  const int tid = threadIdx.x;
  const int w = tid >> 6;
  const int L = tid & 63;
  const int lane16 = L & 15;
  const int quad = L >> 4;
  const int b = blockIdx.z;
  const int ty0 = blockIdx.y * 8;
  const int tx0 = blockIdx.x * 16;
  const float* sb = sin_ + b * 29 * 4096;

  // --- P1: halo load (29 ch x 10 rows x 18 cols, zero-padded), unrolled
  //     register staging: all 21 global loads in flight, then 21 ds_writes.
  {
    float hv[21];
    int hix[21];
#pragma unroll
    for (int it = 0; it < 21; ++it) {
      int l = tid + it * 256;
      int c = l / 180;
      int rem = l - c * 180;
      int r = rem / 18;
      int x = rem - r * 18;
      int gy = ty0 - 1 + r, gx = tx0 - 1 + x;
      bool in = (l < 29 * 180);
      float v = 0.0f;
      if (in && (unsigned)gy < 64u && (unsigned)gx < 64u)
        v = sb[c * 4096 + gy * 64 + gx];
      hv[it] = v;
      hix[it] = in ? (c * 181 + r * 18 + x) : 5249;
    }
#pragma unroll
    for (int it = 0; it < 21; ++it) sS[hix[it]] = hv[it];
  }
  __syncthreads();

  // --- A1 fragments for BOTH row-tiles (permuted K: ps | px,t | py) ---
  const int am0 = w * 32 + lane16;        // row-tile 0: y = 2w
  const int am1 = w * 32 + 16 + lane16;   // row-tile 1: y = 2w+1
  bf16x8 a1h[2][3], a1l[2][3];
#pragma unroll
  for (int tt = 0; tt < 2; ++tt) {
    float vps[8], vpx[8], vpy[8];
#pragma unroll
    for (int j = 0; j < 8; ++j) {
      int c = quad * 8 + j;
      int cc = (c < 29) ? c : 0;
      const float* S = sS + cc * 181 + (2 * w + tt + 1) * 18 + (lane16 + 1);
      float m00 = S[-19], m01 = S[-18], m02 = S[-17];
      float m10 = S[-1],  m11 = S[0],   m12 = S[1];
      float m20 = S[17],  m21 = S[18],  m22 = S[19];
      bool valid = (c < 29);
      vps[j] = valid ? m11 : 0.0f;
      float px = ((m02 - m00) + 2.0f * (m12 - m10) + (m22 - m20)) * 0.125f;
      float py = ((m20 + 2.0f * m21 + m22) - (m00 + 2.0f * m01 + m02)) * 0.125f;
      vpx[j] = valid ? px : ((c == 29) ? tval : 0.0f);
      vpy[j] = valid ? py : 0.0f;
    }
    split8(vps, a1h[tt][0], a1l[tt][0]);
    split8(vpx, a1h[tt][1], a1l[tt][1]);
    split8(vpy, a1h[tt][2], a1l[tt][2]);
  }
  __syncthreads();  // sS dead -> h2 region reusable

  const int L16 = L * 16;

  // --- prologue: seed pw1[nc=0,kc=0] tile loads ---
  bf16x8 n1a, n1b, n1c, n1d;
  {
    const char* g = (const char*)pw1;
    n1a = *(const bf16x8*)(g + L16);
    n1b = *(const bf16x8*)(g + 1024 + L16);
    n1c = *(const bf16x8*)(g + 2048 + L16);
    n1d = *(const bf16x8*)(g + 3072 + L16);
  }

  // --- fire masks for both row-tiles (pure VALU; fills load shadow) ---
  float fire0, fire1;
  {
    int i0 = b * 4096 + (ty0 + 2 * w) * 64 + (tx0 + lane16);
    unsigned bits;
    if (i0 < 32768) bits = tf2x32(fk0, fk1, (unsigned)i0, (unsigned)(i0 + 32768)).a;
    else            bits = tf2x32(fk0, fk1, (unsigned)(i0 - 32768), (unsigned)i0).b;
    fire0 = (bits & 0x80000000u) ? 0.0f : 1.0f;
    int i1 = i0 + 64;
    if (i1 < 32768) bits = tf2x32(fk0, fk1, (unsigned)i1, (unsigned)(i1 + 32768)).a;
    else            bits = tf2x32(fk0, fk1, (unsigned)(i1 - 32768), (unsigned)i1).b;
    fire1 = (bits & 0x80000000u) ? 0.0f : 1.0f;
  }

  // --- fused layer1 -> layer2 over 8 n-chunks of 32 ---
  f32x4 acc2a[8], acc2b[8];
#pragma unroll
  for (int t = 0; t < 8; ++t) {
    acc2a[t] = (f32x4){0.f, 0.f, 0.f, 0.f};
    acc2b[t] = (f32x4){0.f, 0.f, 0.f, 0.f};
  }

#pragma unroll 1
  for (int nc = 0; nc < 8; ++nc) {
    f32x4 c0a = (f32x4){0.f, 0.f, 0.f, 0.f};
    f32x4 c1a = (f32x4){0.f, 0.f, 0.f, 0.f};
    f32x4 c0b = (f32x4){0.f, 0.f, 0.f, 0.f};
    f32x4 c1b = (f32x4){0.f, 0.f, 0.f, 0.f};
#pragma unroll
    for (int kc = 0; kc < 3; ++kc) {
      // consume preloaded tile; issue the next one first (shared by both tts)
      bf16x8 w1a = n1a, w1b = n1b, w1cc = n1c, w1d = n1d;
      {
        const int nt = (kc < 2) ? (nc * 3 + kc + 1) : (((nc + 1) & 7) * 3);
        const char* g = (const char*)pw1 + nt * 4096;
        n1a = *(const bf16x8*)(g + L16);
        n1b = *(const bf16x8*)(g + 1024 + L16);
        n1c = *(const bf16x8*)(g + 2048 + L16);
        n1d = *(const bf16x8*)(g + 3072 + L16);
      }
      __builtin_amdgcn_s_setprio(1);
      // 4 independent chains; per-accumulator order (hh, h*bl, l*bh) kept.
      c0a = MFMA(a1h[0][kc], w1a, c0a);
      c1a = MFMA(a1h[0][kc], w1cc, c1a);
      c0b = MFMA(a1h[1][kc], w1a, c0b);
      c1b = MFMA(a1h[1][kc], w1cc, c1b);
      c0a = MFMA(a1h[0][kc], w1b, c0a);
      c1a = MFMA(a1h[0][kc], w1d, c1a);
      c0b = MFMA(a1h[1][kc], w1b, c0b);
      c1b = MFMA(a1h[1][kc], w1d, c1b);
      c0a = MFMA(a1l[0][kc], w1a, c0a);
      c1a = MFMA(a1l[0][kc], w1cc, c1a);
      c0b = MFMA(a1l[1][kc], w1a, c0b);
      c1b = MFMA(a1l[1][kc], w1cc, c1b);
      __builtin_amdgcn_s_setprio(0);
    }

    // pw2 pipeline (depth 2): issue t=0,1 tiles BEFORE the h1 epilogue.
    const char* g2 = (const char*)pw2 + nc * 16384;
    bf16x8 p0h = *(const bf16x8*)(g2 + L16);
    bf16x8 p0l = *(const bf16x8*)(g2 + 1024 + L16);
    bf16x8 p1h = *(const bf16x8*)(g2 + 2048 + L16);
    bf16x8 p1l = *(const bf16x8*)(g2 + 3072 + L16);

    // bias + leaky + split -> h1 planes, both row-tiles (wave-private rows)
    float bv0 = b1[nc * 32 + lane16];
    float bv1 = b1[nc * 32 + 16 + lane16];
#pragma unroll
    for (int tt = 0; tt < 2; ++tt) {
      f32x4 cc0 = tt ? c0b : c0a;
      f32x4 cc1 = tt ? c1b : c1a;
#pragma unroll
      for (int r = 0; r < 4; ++r) {
        int m = w * 32 + tt * 16 + quad * 4 + r;
        float v0 = leaky(cc0[r] + bv0);
        float v1 = leaky(cc1[r] + bv1);
        unsigned ph = cvtpk(v0, v1);
        float r0 = v0 - __uint_as_float(ph << 16);
        float r1 = v1 - __uint_as_float(ph & 0xFFFF0000u);
        unsigned pl = cvtpk(r0, r1);
        *(unsigned short*)(h1h + m * 64 + swz64(m, lane16 * 2)) = (unsigned short)ph;
        *(unsigned short*)(h1h + m * 64 + swz64(m, 32 + lane16 * 2)) = (unsigned short)(ph >> 16);
        *(unsigned short*)(h1l + m * 64 + swz64(m, lane16 * 2)) = (unsigned short)pl;
        *(unsigned short*)(h1l + m * 64 + swz64(m, 32 + lane16 * 2)) = (unsigned short)(pl >> 16);
      }
    }
    // layer2 A-frags for both row-tiles (same wave's rows; lgkm-ordered)
    bf16x8 ah0 = *(const bf16x8*)(h1h + am0 * 64 + swz64(am0, quad * 16));
    bf16x8 al0 = *(const bf16x8*)(h1l + am0 * 64 + swz64(am0, quad * 16));
    bf16x8 ah1 = *(const bf16x8*)(h1h + am1 * 64 + swz64(am1, quad * 16));
    bf16x8 al1 = *(const bf16x8*)(h1l + am1 * 64 + swz64(am1, quad * 16));
#pragma unroll
    for (int t = 0; t < 8; ++t) {
      bf16x8 bh = (t & 1) ? p1h : p0h;
      bf16x8 bl = (t & 1) ? p1l : p0l;
      if (t < 6) {  // refill the slot just consumed with tile t+2
        const char* g = g2 + (t + 2) * 2048;
        if (t & 1) {
          p1h = *(const bf16x8*)(g + L16);
          p1l = *(const bf16x8*)(g + 1024 + L16);
        } else {
          p0h = *(const bf16x8*)(g + L16);
          p0l = *(const bf16x8*)(g + 1024 + L16);
        }
      }
      __builtin_amdgcn_s_setprio(1);
      acc2a[t] = MFMA(ah0, bh, acc2a[t]);
      acc2b[t] = MFMA(ah1, bh, acc2b[t]);
      acc2a[t] = MFMA(ah0, bl, acc2a[t]);
      acc2b[t] = MFMA(ah1, bl, acc2b[t]);
      acc2a[t] = MFMA(al0, bh, acc2a[t]);
      acc2b[t] = MFMA(al1, bh, acc2b[t]);
      __builtin_amdgcn_s_setprio(0);
    }
  }

  // --- h2 epilogue: leaky + split -> h2 planes, both row-tiles ---
#pragma unroll
  for (int tt = 0; tt < 2; ++tt) {
#pragma unroll
    for (int t = 0; t < 8; t += 2) {
#pragma unroll
      for (int r = 0; r < 4; ++r) {
        int m = w * 32 + tt * 16 + quad * 4 + r;
        float va = leaky(tt ? acc2b[t][r] : acc2a[t][r]);
        float vb = leaky(tt ? acc2b[t + 1][r] : acc2a[t + 1][r]);
        unsigned ph = cvtpk(va, vb);
        float ra = va - __uint_as_float(ph << 16);
        float rb = vb - __uint_as_float(ph & 0xFFFF0000u);
        unsigned pl = cvtpk(ra, rb);
        int offa = (t * 16 + lane16) * 2;
        int offb = ((t + 1) * 16 + lane16) * 2;
        *(unsigned short*)(h2h + m * 256 + swz256(m, offa)) = (unsigned short)ph;
        *(unsigned short*)(h2h + m * 256 + swz256(m, offb)) = (unsigned short)(ph >> 16);
        *(unsigned short*)(h2l + m * 256 + swz256(m, offa)) = (unsigned short)pl;
        *(unsigned short*)(h2l + m * 256 + swz256(m, offb)) = (unsigned short)(pl >> 16);
      }
    }
  }

  // --- layer3: 2 C-tiles (N=32) x 2 row-tiles, K=128; pw3 depth-1 pipeline ---
  bf16x8 m0, m1, m2, m3;
  {
    const char* g = (const char*)pw3;
    m0 = *(const bf16x8*)(g + L16);
    m1 = *(const bf16x8*)(g + 1024 + L16);
    m2 = *(const bf16x8*)(g + 2048 + L16);
    m3 = *(const bf16x8*)(g + 3072 + L16);
  }
  f32x4 d0a = (f32x4){0.f, 0.f, 0.f, 0.f};
  f32x4 d1a = (f32x4){0.f, 0.f, 0.f, 0.f};
  f32x4 d0b = (f32x4){0.f, 0.f, 0.f, 0.f};
  f32x4 d1b = (f32x4){0.f, 0.f, 0.f, 0.f};
#pragma unroll
  for (int kc = 0; kc < 4; ++kc) {
    bf16x8 q0 = m0, q1 = m1, q2 = m2, q3 = m3;
    if (kc < 3) {
      const char* g = (const char*)pw3 + (kc + 1) * 4096;
      m0 = *(const bf16x8*)(g + L16);
      m1 = *(const bf16x8*)(g + 1024 + L16);
      m2 = *(const bf16x8*)(g + 2048 + L16);
      m3 = *(const bf16x8*)(g + 3072 + L16);
    }
    bf16x8 ah0 = *(const bf16x8*)(h2h + am0 * 256 + swz256(am0, kc * 64 + quad * 16));
    bf16x8 al0 = *(const bf16x8*)(h2l + am0 * 256 + swz256(am0, kc * 64 + quad * 16));
    bf16x8 ah1 = *(const bf16x8*)(h2h + am1 * 256 + swz256(am1, kc * 64 + quad * 16));
    bf16x8 al1 = *(const bf16x8*)(h2l + am1 * 256 + swz256(am1, kc * 64 + quad * 16));
    __builtin_amdgcn_s_setprio(1);
    d0a = MFMA(ah0, q0, d0a);
    d1a = MFMA(ah0, q2, d1a);
    d0b = MFMA(ah1, q0, d0b);
    d1b = MFMA(ah1, q2, d1b);
    d0a = MFMA(ah0, q1, d0a);
    d1a = MFMA(ah0, q3, d1a);
    d0b = MFMA(ah1, q1, d0b);
    d1b = MFMA(ah1, q3, d1b);
    d0a = MFMA(al0, q0, d0a);
    d1a = MFMA(al0, q2, d1a);
    d0b = MFMA(al1, q0, d0b);
    d1b = MFMA(al1, q2, d1b);
    __builtin_amdgcn_s_setprio(0);
  }

  // --- epilogue: residual + fire (fire values pulled via shuffle) ---
  float fr0[4], fr1[4];
#pragma unroll
  for (int r = 0; r < 4; ++r) {
    fr0[r] = __shfl(fire0, quad * 4 + r, 64);
    fr1[r] = __shfl(fire1, quad * 4 + r, 64);
  }
  int gxq = tx0 + quad * 4;
  float* ob = sout + b * 29 * 4096;
#pragma unroll
  for (int tt = 0; tt < 2; ++tt) {
    int gy = ty0 + 2 * w + tt;
#pragma unroll
    for (int t3 = 0; t3 < 2; ++t3) {
      int c = t3 * 16 + lane16;
      if (c >= 3 && c <= 28) {
        float4 so = *(const float4*)(sb + c * 4096 + gy * 64 + gxq);
        f32x4 d = tt ? (t3 ? d1b : d0b) : (t3 ? d1a : d0a);
        const float* fr = tt ? fr1 : fr0;
        float4 o;
        o.x = fmaf(fr[0], d[0], so.x);
        o.y = fmaf(fr[1], d[1], so.y);
        o.z = fmaf(fr[2], d[2], so.z);
        o.w = fmaf(fr[3], d[3], so.w);
        *(float4*)(ob + c * 4096 + gy * 64 + gxq) = o;
      }
    }
  }
}

// ---------------------------------------------------------------------------
__global__ __launch_bounds__(256) void finalize(const float* __restrict__ s,
                                                float* __restrict__ out) {
  __shared__ float red[256];
  __shared__ float ls[10];
  int b = blockIdx.x, tid = threadIdx.x;
  const float* sb = s + b * 29 * 4096;
  for (int o = 0; o < 10; ++o) {
    const float* ch = sb + (19 + o) * 4096;
    float p = 0.0f;
    for (int i = tid; i < 4096; i += 256) p += ch[i];
    red[tid] = p;
    __syncthreads();
    for (int st = 128; st > 0; st >>= 1) {
      if (tid < st) red[tid] += red[tid + st];
      __syncthreads();
    }
    if (tid == 0) ls[o] = red[0] * (1.0f / 4096.0f);
    __syncthreads();
  }
  if (tid == 0) {
    float m = ls[0];
    for (int o = 1; o < 10; ++o) m = fmaxf(m, ls[o]);
    float e[10], sum = 0.0f;
    for (int o = 0; o < 10; ++o) { e[o] = expf(ls[o] - m); sum += e[o]; }
    for (int o = 0; o < 10; ++o) out[b * 10 + o] = e[o] / sum;
  }
}

// ---------------------------------------------------------------------------
extern "C" void kernel_launch(void* const* d_in, const int* in_sizes, int n_in,
                              void* d_out, int out_size, void* d_ws, size_t ws_size,
                              hipStream_t stream) {
  const float* x  = (const float*)d_in[0];
  const float* w1 = (const float*)d_in[1];
  const float* b1 = (const float*)d_in[2];
  const float* w2 = (const float*)d_in[3];
  const float* w3 = (const float*)d_in[4];
  const int STEPS = 20;  // setup_inputs() fixes steps=20

  const size_t STATE = (size_t)16 * 29 * 4096;
  float* ws = (float*)d_ws;
  float* s0 = ws;
  float* s1 = ws + STATE;
  unsigned short* pw1 = (unsigned short*)(ws + 2 * STATE);  // 96*512 shorts
  unsigned short* pw2 = pw1 + 96 * 512;                      // 128*512
  unsigned short* pw3 = pw2 + 128 * 512;                     // 16*512
  (void)ws_size; (void)n_in; (void)in_sizes; (void)out_size;

  prep_weights<<<256, 256, 0, stream>>>(w1, w2, w3, pw1, pw2, pw3);

  U2 hk = tf2x32(0u, 42u, 0u, 10000u);  // fold_in(key(42), 10000)
  init_state<<<(16 * 29 * 4096 + 255) / 256, 256, 0, stream>>>(x, s0, s1, hk.a, hk.b);

  for (int s = 0; s < STEPS; ++s) {
    U2 fk = tf2x32(0u, 42u, 0u, (unsigned)s);  // fold_in(key(42), step)
    float tval = (float)s / 100.0f;
    const float* in = (s & 1) ? s1 : s0;
    float* out = (s & 1) ? s0 : s1;
    dim3 grid(4, 8, 16);
    nca_step<<<grid, 256, 0, stream>>>(in, out, pw1, b1, pw2, pw3, tval, fk.a, fk.b);
  }
  finalize<<<16, 256, 0, stream>>>(s0, (float*)d_out);
}

// Round 4
// 692.485 us; speedup vs baseline: 1.4226x; 1.0617x over previous
//
#include <hip/hip_runtime.h>

// ---------------------------------------------------------------------------
// ClassificationNCA — Round 8: finalize rewrite (two-stage parallel reduce).
// R7's nca_step kept byte-identical (M=32/wave, 128-pixel blocks, LDS 81920,
// 2 blocks/CU). finalize was the top dispatch (45.9 us, 16 blocks, 0.6% occ,
// 80+ barriers); replaced by reduce_ch (160 blocks, float4 + shfl reduce)
// + softmax10 (16 one-wave blocks). Expected finalize cost: < 8 us.
// ---------------------------------------------------------------------------

#define ROTL32(x, d) (((x) << (d)) | ((x) >> (32 - (d))))

struct U2 { unsigned a, b; };

__host__ __device__ inline U2 tf2x32(unsigned k0, unsigned k1, unsigned c0, unsigned c1) {
  unsigned ks2 = k0 ^ k1 ^ 0x1BD11BDAu;
  unsigned x0 = c0 + k0;
  unsigned x1 = c1 + k1;
#define TF_ROUND4(r0, r1, r2, r3)                                              \
  x0 += x1; x1 = ROTL32(x1, r0); x1 ^= x0;                                     \
  x0 += x1; x1 = ROTL32(x1, r1); x1 ^= x0;                                     \
  x0 += x1; x1 = ROTL32(x1, r2); x1 ^= x0;                                     \
  x0 += x1; x1 = ROTL32(x1, r3); x1 ^= x0;
  TF_ROUND4(13, 15, 26, 6)
  x0 += k1;  x1 += ks2 + 1u;
  TF_ROUND4(17, 29, 16, 24)
  x0 += ks2; x1 += k0 + 2u;
  TF_ROUND4(13, 15, 26, 6)
  x0 += k0;  x1 += k1 + 3u;
  TF_ROUND4(17, 29, 16, 24)
  x0 += k1;  x1 += ks2 + 4u;
  TF_ROUND4(13, 15, 26, 6)
  x0 += ks2; x1 += k0 + 5u;
#undef TF_ROUND4
  U2 r; r.a = x0; r.b = x1; return r;
}

__device__ inline float erfinv_xla(float x) {
  float w = -log1pf(-x * x);
  float p;
  if (w < 5.0f) {
    w -= 2.5f;
    p = 2.81022636e-08f;
    p = fmaf(p, w, 3.43273939e-07f);
    p = fmaf(p, w, -3.5233877e-06f);
    p = fmaf(p, w, -4.39150654e-06f);
    p = fmaf(p, w, 0.00021858087f);
    p = fmaf(p, w, -0.00125372503f);
    p = fmaf(p, w, -0.00417768164f);
    p = fmaf(p, w, 0.246640727f);
    p = fmaf(p, w, 1.50140941f);
  } else {
    w = sqrtf(w) - 3.0f;
    p = -0.000200214257f;
    p = fmaf(p, w, 0.000100950558f);
    p = fmaf(p, w, 0.00134934322f);
    p = fmaf(p, w, -0.00367342844f);
    p = fmaf(p, w, 0.00573950773f);
    p = fmaf(p, w, -0.0076224613f);
    p = fmaf(p, w, 0.00943887047f);
    p = fmaf(p, w, 1.00167406f);
    p = fmaf(p, w, 2.83297682f);
  }
  return p * x;
}

// Exact rewrite of (v>=0 ? v : .01v).
__device__ inline float leaky(float v) { return fmaxf(v, 0.01f * v); }

typedef __attribute__((ext_vector_type(8))) short bf16x8;
typedef __attribute__((ext_vector_type(4))) float f32x4;
typedef __attribute__((ext_vector_type(4))) unsigned int u32x4;

__host__ __device__ inline unsigned short bf16_rne(float x) {
  unsigned u = __float_as_uint(x);
  return (unsigned short)((u + 0x7FFFu + ((u >> 16) & 1u)) >> 16);
}

// v_cvt_pk_bf16_f32: dst[15:0]=bf16_rne(a), dst[31:16]=bf16_rne(b).
__device__ inline unsigned cvtpk(float a, float b) {
  unsigned r;
  asm("v_cvt_pk_bf16_f32 %0, %1, %2" : "=v"(r) : "v"(a), "v"(b));
  return r;
}

union Frag8 { u32x4 u; bf16x8 v; };

__device__ inline void split8(const float v[8], bf16x8& hi, bf16x8& lo) {
  Frag8 H, L;
#pragma unroll
  for (int j = 0; j < 8; j += 2) {
    unsigned p = cvtpk(v[j], v[j + 1]);
    H.u[j >> 1] = p;
    float r0 = v[j]     - __uint_as_float(p << 16);
    float r1 = v[j + 1] - __uint_as_float(p & 0xFFFF0000u);
    L.u[j >> 1] = cvtpk(r0, r1);
  }
  hi = H.v;
  lo = L.v;
}

// XOR swizzles: 16B groups; 4-group window (64B rows) / 8-group window (256B).
__device__ inline int swz64(int m, int off) {
  int g = (off >> 4) ^ (m & 3);
  return (g << 4) | (off & 15);
}
__device__ inline int swz256(int m, int off) {
  int g = off >> 4;
  g = (g & ~7) | ((g ^ (m & 7)) & 7);
  return (g << 4) | (off & 15);
}

#define MFMA(a, b, c) __builtin_amdgcn_mfma_f32_16x16x32_bf16((a), (b), (c), 0, 0, 0)

// ---------------------------------------------------------------------------
// Weight prep: fragment-major packed B-tiles (1 KB/tile), unchanged.
// ---------------------------------------------------------------------------
__global__ void prep_weights(const float* __restrict__ w1, const float* __restrict__ w2,
                             const float* __restrict__ w3,
                             unsigned short* __restrict__ pw1,
                             unsigned short* __restrict__ pw2,
                             unsigned short* __restrict__ pw3) {
  int i = blockIdx.x * 256 + threadIdx.x;
  int e = i & 511, L = e >> 3, j = e & 7;
  int kq = (L >> 4) * 8 + j;   // k within 32-chunk
  int ln = L & 15;             // n within 16-tile
  if (i < 96 * 512) {          // pw1: [nc(8)][kc(3)][f(4)]
    int tile = i >> 9;
    int f = tile & 3, kc = (tile >> 2) % 3, nc = tile / 12;
    int n = nc * 32 + (f >> 1) * 16 + ln;
    int src;
    if (kc == 0)      src = (kq < 29) ? kq : -1;
    else if (kc == 1) src = (kq < 29) ? 29 + kq : ((kq == 29) ? 87 : -1);
    else              src = (kq < 29) ? 58 + kq : -1;
    float v = (src >= 0) ? w1[n * 88 + src] : 0.0f;
    unsigned short h = bf16_rne(v);
    pw1[i] = (f & 1) ? bf16_rne(v - __uint_as_float(((unsigned)h) << 16)) : h;
  }
  if (i < 128 * 512) {         // pw2: [nc(8)][t(8)][h,l]
    int tile = i >> 9;
    int hl = tile & 1, t = (tile >> 1) & 7, nc = tile >> 4;
    int n = t * 16 + ln;
    int k = nc * 32 + kq;
    float v = w2[n * 256 + k];
    unsigned short h = bf16_rne(v);
    pw2[i] = hl ? bf16_rne(v - __uint_as_float(((unsigned)h) << 16)) : h;
  }
  if (i < 16 * 512) {          // pw3: [kc(4)][f(4)]
    int tile = i >> 9;
    int f = tile & 3, kc = tile >> 2;
    int n = (f >> 1) * 16 + ln;
    int k = kc * 32 + kq;
    float v = (n < 29) ? w3[n * 128 + k] : 0.0f;
    unsigned short h = bf16_rne(v);
    pw3[i] = (f & 1) ? bf16_rne(v - __uint_as_float(((unsigned)h) << 16)) : h;
  }
}

// ---------------------------------------------------------------------------
__global__ void init_state(const float* __restrict__ x, float* __restrict__ s0,
                           float* __restrict__ s1, unsigned hk0, unsigned hk1) {
  int idx = blockIdx.x * 256 + threadIdx.x;
  if (idx >= 16 * 29 * 4096) return;
  int pix = idx & 4095;
  int c = (idx >> 12) % 29;
  int b = idx / (4096 * 29);
  float v;
  if (c < 3) {
    v = x[(b * 3 + c) * 4096 + pix];
    s1[idx] = v;
  } else if (c < 19) {
    int ch = c - 3;
    int i = (b * 16 + ch) * 4096 + pix;
    const int half = 131072;
    unsigned bits;
    if (i < half) bits = tf2x32(hk0, hk1, (unsigned)i, (unsigned)(i + half)).a;
    else          bits = tf2x32(hk0, hk1, (unsigned)(i - half), (unsigned)i).b;
    float f = __uint_as_float((bits >> 9) | 0x3F800000u) - 1.0f;
    const float lo = -0x1.fffffep-1f;
    float u = fmaxf(lo, fmaf(f, 2.0f, lo));
    v = fmaf(0.225f, 1.41421356237f * erfinv_xla(u), 0.5f);
  } else {
    v = 0.0f;
  }
  s0[idx] = v;
}

// ---------------------------------------------------------------------------
// One NCA step, 128-pixel blocks (8 rows x 16 cols). LDS map (bytes), 81920:
//   [0     ..  8192)  h1h  ushort[128][32], row 64 B, swz64
//   [8192  .. 16384)  h1l  ushort[128][32]
//   [16384 .. 49152)  h2h  ushort[128][128], row 256 B, swz256
//   [49152 .. 81920)  h2l  ushort[128][128]
//   sS halo float[29][stride 181] (10 rows x 18 cols) overlays h2h region
//   (20996 B < 32768; dead before first h2 write). Dump slot 5249.
// Wave w owns pixel rows y = {2w, 2w+1} (M rows [w*32, w*32+32)).
// ---------------------------------------------------------------------------
__global__ __launch_bounds__(256, 2) void nca_step(
    const float* __restrict__ sin_, float* __restrict__ sout,
    const unsigned short* __restrict__ pw1, const float* __restrict__ b1,
    const unsigned short* __restrict__ pw2, const unsigned short* __restrict__ pw3,
    float tval, unsigned fk0, unsigned fk1) {
  __shared__ __align__(16) char lds[81920];
  char* h1h = lds;
  char* h1l = lds + 8192;
  char* h2h = lds + 16384;
  char* h2l = lds + 49152;
  float* sS = (float*)(lds + 16384);   // 29 ch x 181 floats

  const int tid = threadIdx.x;
  const int w = tid >> 6;
  const int L = tid & 63;
  const int lane16 = L & 15;
  const int quad = L >> 4;
  const int b = blockIdx.z;
  const int ty0 = blockIdx.y * 8;
  const int tx0 = blockIdx.x * 16;
  const float* sb = sin_ + b * 29 * 4096;

  // --- P1: halo load (29 ch x 10 rows x 18 cols, zero-padded), unrolled
  //     register staging: all 21 global loads in flight, then 21 ds_writes.
  {
    float hv[21];
    int hix[21];
#pragma unroll
    for (int it = 0; it < 21; ++it) {
      int l = tid + it * 256;
      int c = l / 180;
      int rem = l - c * 180;
      int r = rem / 18;
      int x = rem - r * 18;
      int gy = ty0 - 1 + r, gx = tx0 - 1 + x;
      bool in = (l < 29 * 180);
      float v = 0.0f;
      if (in && (unsigned)gy < 64u && (unsigned)gx < 64u)
        v = sb[c * 4096 + gy * 64 + gx];
      hv[it] = v;
      hix[it] = in ? (c * 181 + r * 18 + x) : 5249;
    }
#pragma unroll
    for (int it = 0; it < 21; ++it) sS[hix[it]] = hv[it];
  }
  __syncthreads();

  // --- A1 fragments for BOTH row-tiles (permuted K: ps | px,t | py) ---
  const int am0 = w * 32 + lane16;        // row-tile 0: y = 2w
  const int am1 = w * 32 + 16 + lane16;   // row-tile 1: y = 2w+1
  bf16x8 a1h[2][3], a1l[2][3];
#pragma unroll
  for (int tt = 0; tt < 2; ++tt) {
    float vps[8], vpx[8], vpy[8];
#pragma unroll
    for (int j = 0; j < 8; ++j) {
      int c = quad * 8 + j;
      int cc = (c < 29) ? c : 0;
      const float* S = sS + cc * 181 + (2 * w + tt + 1) * 18 + (lane16 + 1);
      float m00 = S[-19], m01 = S[-18], m02 = S[-17];
      float m10 = S[-1],  m11 = S[0],   m12 = S[1];
      float m20 = S[17],  m21 = S[18],  m22 = S[19];
      bool valid = (c < 29);
      vps[j] = valid ? m11 : 0.0f;
      float px = ((m02 - m00) + 2.0f * (m12 - m10) + (m22 - m20)) * 0.125f;
      float py = ((m20 + 2.0f * m21 + m22) - (m00 + 2.0f * m01 + m02)) * 0.125f;
      vpx[j] = valid ? px : ((c == 29) ? tval : 0.0f);
      vpy[j] = valid ? py : 0.0f;
    }
    split8(vps, a1h[tt][0], a1l[tt][0]);
    split8(vpx, a1h[tt][1], a1l[tt][1]);
    split8(vpy, a1h[tt][2], a1l[tt][2]);
  }
  __syncthreads();  // sS dead -> h2 region reusable

  const int L16 = L * 16;

  // --- prologue: seed pw1[nc=0,kc=0] tile loads ---
  bf16x8 n1a, n1b, n1c, n1d;
  {
    const char* g = (const char*)pw1;
    n1a = *(const bf16x8*)(g + L16);
    n1b = *(const bf16x8*)(g + 1024 + L16);
    n1c = *(const bf16x8*)(g + 2048 + L16);
    n1d = *(const bf16x8*)(g + 3072 + L16);
  }

  // --- fire masks for both row-tiles (pure VALU; fills load shadow) ---
  float fire0, fire1;
  {
    int i0 = b * 4096 + (ty0 + 2 * w) * 64 + (tx0 + lane16);
    unsigned bits;
    if (i0 < 32768) bits = tf2x32(fk0, fk1, (unsigned)i0, (unsigned)(i0 + 32768)).a;
    else            bits = tf2x32(fk0, fk1, (unsigned)(i0 - 32768), (unsigned)i0).b;
    fire0 = (bits & 0x80000000u) ? 0.0f : 1.0f;
    int i1 = i0 + 64;
    if (i1 < 32768) bits = tf2x32(fk0, fk1, (unsigned)i1, (unsigned)(i1 + 32768)).a;
    else            bits = tf2x32(fk0, fk1, (unsigned)(i1 - 32768), (unsigned)i1).b;
    fire1 = (bits & 0x80000000u) ? 0.0f : 1.0f;
  }

  // --- fused layer1 -> layer2 over 8 n-chunks of 32 ---
  f32x4 acc2a[8], acc2b[8];
#pragma unroll
  for (int t = 0; t < 8; ++t) {
    acc2a[t] = (f32x4){0.f, 0.f, 0.f, 0.f};
    acc2b[t] = (f32x4){0.f, 0.f, 0.f, 0.f};
  }

#pragma unroll 1
  for (int nc = 0; nc < 8; ++nc) {
    f32x4 c0a = (f32x4){0.f, 0.f, 0.f, 0.f};
    f32x4 c1a = (f32x4){0.f, 0.f, 0.f, 0.f};
    f32x4 c0b = (f32x4){0.f, 0.f, 0.f, 0.f};
    f32x4 c1b = (f32x4){0.f, 0.f, 0.f, 0.f};
#pragma unroll
    for (int kc = 0; kc < 3; ++kc) {
      // consume preloaded tile; issue the next one first (shared by both tts)
      bf16x8 w1a = n1a, w1b = n1b, w1cc = n1c, w1d = n1d;
      {
        const int nt = (kc < 2) ? (nc * 3 + kc + 1) : (((nc + 1) & 7) * 3);
        const char* g = (const char*)pw1 + nt * 4096;
        n1a = *(const bf16x8*)(g + L16);
        n1b = *(const bf16x8*)(g + 1024 + L16);
        n1c = *(const bf16x8*)(g + 2048 + L16);
        n1d = *(const bf16x8*)(g + 3072 + L16);
      }
      __builtin_amdgcn_s_setprio(1);
      // 4 independent chains; per-accumulator order (hh, h*bl, l*bh) kept.
      c0a = MFMA(a1h[0][kc], w1a, c0a);
      c1a = MFMA(a1h[0][kc], w1cc, c1a);
      c0b = MFMA(a1h[1][kc], w1a, c0b);
      c1b = MFMA(a1h[1][kc], w1cc, c1b);
      c0a = MFMA(a1h[0][kc], w1b, c0a);
      c1a = MFMA(a1h[0][kc], w1d, c1a);
      c0b = MFMA(a1h[1][kc], w1b, c0b);
      c1b = MFMA(a1h[1][kc], w1d, c1b);
      c0a = MFMA(a1l[0][kc], w1a, c0a);
      c1a = MFMA(a1l[0][kc], w1cc, c1a);
      c0b = MFMA(a1l[1][kc], w1a, c0b);
      c1b = MFMA(a1l[1][kc], w1cc, c1b);
      __builtin_amdgcn_s_setprio(0);
    }

    // pw2 pipeline (depth 2): issue t=0,1 tiles BEFORE the h1 epilogue.
    const char* g2 = (const char*)pw2 + nc * 16384;
    bf16x8 p0h = *(const bf16x8*)(g2 + L16);
    bf16x8 p0l = *(const bf16x8*)(g2 + 1024 + L16);
    bf16x8 p1h = *(const bf16x8*)(g2 + 2048 + L16);
    bf16x8 p1l = *(const bf16x8*)(g2 + 3072 + L16);

    // bias + leaky + split -> h1 planes, both row-tiles (wave-private rows)
    float bv0 = b1[nc * 32 + lane16];
    float bv1 = b1[nc * 32 + 16 + lane16];
#pragma unroll
    for (int tt = 0; tt < 2; ++tt) {
      f32x4 cc0 = tt ? c0b : c0a;
      f32x4 cc1 = tt ? c1b : c1a;
#pragma unroll
      for (int r = 0; r < 4; ++r) {
        int m = w * 32 + tt * 16 + quad * 4 + r;
        float v0 = leaky(cc0[r] + bv0);
        float v1 = leaky(cc1[r] + bv1);
        unsigned ph = cvtpk(v0, v1);
        float r0 = v0 - __uint_as_float(ph << 16);
        float r1 = v1 - __uint_as_float(ph & 0xFFFF0000u);
        unsigned pl = cvtpk(r0, r1);
        *(unsigned short*)(h1h + m * 64 + swz64(m, lane16 * 2)) = (unsigned short)ph;
        *(unsigned short*)(h1h + m * 64 + swz64(m, 32 + lane16 * 2)) = (unsigned short)(ph >> 16);
        *(unsigned short*)(h1l + m * 64 + swz64(m, lane16 * 2)) = (unsigned short)pl;
        *(unsigned short*)(h1l + m * 64 + swz64(m, 32 + lane16 * 2)) = (unsigned short)(pl >> 16);
      }
    }
    // layer2 A-frags for both row-tiles (same wave's rows; lgkm-ordered)
    bf16x8 ah0 = *(const bf16x8*)(h1h + am0 * 64 + swz64(am0, quad * 16));
    bf16x8 al0 = *(const bf16x8*)(h1l + am0 * 64 + swz64(am0, quad * 16));
    bf16x8 ah1 = *(const bf16x8*)(h1h + am1 * 64 + swz64(am1, quad * 16));
    bf16x8 al1 = *(const bf16x8*)(h1l + am1 * 64 + swz64(am1, quad * 16));
#pragma unroll
    for (int t = 0; t < 8; ++t) {
      bf16x8 bh = (t & 1) ? p1h : p0h;
      bf16x8 bl = (t & 1) ? p1l : p0l;
      if (t < 6) {  // refill the slot just consumed with tile t+2
        const char* g = g2 + (t + 2) * 2048;
        if (t & 1) {
          p1h = *(const bf16x8*)(g + L16);
          p1l = *(const bf16x8*)(g + 1024 + L16);
        } else {
          p0h = *(const bf16x8*)(g + L16);
          p0l = *(const bf16x8*)(g + 1024 + L16);
        }
      }
      __builtin_amdgcn_s_setprio(1);
      acc2a[t] = MFMA(ah0, bh, acc2a[t]);
      acc2b[t] = MFMA(ah1, bh, acc2b[t]);
      acc2a[t] = MFMA(ah0, bl, acc2a[t]);
      acc2b[t] = MFMA(ah1, bl, acc2b[t]);
      acc2a[t] = MFMA(al0, bh, acc2a[t]);
      acc2b[t] = MFMA(al1, bh, acc2b[t]);
      __builtin_amdgcn_s_setprio(0);
    }
  }

  // --- h2 epilogue: leaky + split -> h2 planes, both row-tiles ---
#pragma unroll
  for (int tt = 0; tt < 2; ++tt) {
#pragma unroll
    for (int t = 0; t < 8; t += 2) {
#pragma unroll
      for (int r = 0; r < 4; ++r) {
        int m = w * 32 + tt * 16 + quad * 4 + r;
        float va = leaky(tt ? acc2b[t][r] : acc2a[t][r]);
        float vb = leaky(tt ? acc2b[t + 1][r] : acc2a[t + 1][r]);
        unsigned ph = cvtpk(va, vb);
        float ra = va - __uint_as_float(ph << 16);
        float rb = vb - __uint_as_float(ph & 0xFFFF0000u);
        unsigned pl = cvtpk(ra, rb);
        int offa = (t * 16 + lane16) * 2;
        int offb = ((t + 1) * 16 + lane16) * 2;
        *(unsigned short*)(h2h + m * 256 + swz256(m, offa)) = (unsigned short)ph;
        *(unsigned short*)(h2h + m * 256 + swz256(m, offb)) = (unsigned short)(ph >> 16);
        *(unsigned short*)(h2l + m * 256 + swz256(m, offa)) = (unsigned short)pl;
        *(unsigned short*)(h2l + m * 256 + swz256(m, offb)) = (unsigned short)(pl >> 16);
      }
    }
  }

  // --- layer3: 2 C-tiles (N=32) x 2 row-tiles, K=128; pw3 depth-1 pipeline ---
  bf16x8 m0, m1, m2, m3;
  {
    const char* g = (const char*)pw3;
    m0 = *(const bf16x8*)(g + L16);
    m1 = *(const bf16x8*)(g + 1024 + L16);
    m2 = *(const bf16x8*)(g + 2048 + L16);
    m3 = *(const bf16x8*)(g + 3072 + L16);
  }
  f32x4 d0a = (f32x4){0.f, 0.f, 0.f, 0.f};
  f32x4 d1a = (f32x4){0.f, 0.f, 0.f, 0.f};
  f32x4 d0b = (f32x4){0.f, 0.f, 0.f, 0.f};
  f32x4 d1b = (f32x4){0.f, 0.f, 0.f, 0.f};
#pragma unroll
  for (int kc = 0; kc < 4; ++kc) {
    bf16x8 q0 = m0, q1 = m1, q2 = m2, q3 = m3;
    if (kc < 3) {
      const char* g = (const char*)pw3 + (kc + 1) * 4096;
      m0 = *(const bf16x8*)(g + L16);
      m1 = *(const bf16x8*)(g + 1024 + L16);
      m2 = *(const bf16x8*)(g + 2048 + L16);
      m3 = *(const bf16x8*)(g + 3072 + L16);
    }
    bf16x8 ah0 = *(const bf16x8*)(h2h + am0 * 256 + swz256(am0, kc * 64 + quad * 16));
    bf16x8 al0 = *(const bf16x8*)(h2l + am0 * 256 + swz256(am0, kc * 64 + quad * 16));
    bf16x8 ah1 = *(const bf16x8*)(h2h + am1 * 256 + swz256(am1, kc * 64 + quad * 16));
    bf16x8 al1 = *(const bf16x8*)(h2l + am1 * 256 + swz256(am1, kc * 64 + quad * 16));
    __builtin_amdgcn_s_setprio(1);
    d0a = MFMA(ah0, q0, d0a);
    d1a = MFMA(ah0, q2, d1a);
    d0b = MFMA(ah1, q0, d0b);
    d1b = MFMA(ah1, q2, d1b);
    d0a = MFMA(ah0, q1, d0a);
    d1a = MFMA(ah0, q3, d1a);
    d0b = MFMA(ah1, q1, d0b);
    d1b = MFMA(ah1, q3, d1b);
    d0a = MFMA(al0, q0, d0a);
    d1a = MFMA(al0, q2, d1a);
    d0b = MFMA(al1, q0, d0b);
    d1b = MFMA(al1, q2, d1b);
    __builtin_amdgcn_s_setprio(0);
  }

  // --- epilogue: residual + fire (fire values pulled via shuffle) ---
  float fr0[4], fr1[4];
#pragma unroll
  for (int r = 0; r < 4; ++r) {
    fr0[r] = __shfl(fire0, quad * 4 + r, 64);
    fr1[r] = __shfl(fire1, quad * 4 + r, 64);
  }
  int gxq = tx0 + quad * 4;
  float* ob = sout + b * 29 * 4096;
#pragma unroll
  for (int tt = 0; tt < 2; ++tt) {
    int gy = ty0 + 2 * w + tt;
#pragma unroll
    for (int t3 = 0; t3 < 2; ++t3) {
      int c = t3 * 16 + lane16;
      if (c >= 3 && c <= 28) {
        float4 so = *(const float4*)(sb + c * 4096 + gy * 64 + gxq);
        f32x4 d = tt ? (t3 ? d1b : d0b) : (t3 ? d1a : d0a);
        const float* fr = tt ? fr1 : fr0;
        float4 o;
        o.x = fmaf(fr[0], d[0], so.x);
        o.y = fmaf(fr[1], d[1], so.y);
        o.z = fmaf(fr[2], d[2], so.z);
        o.w = fmaf(fr[3], d[3], so.w);
        *(float4*)(ob + c * 4096 + gy * 64 + gxq) = o;
      }
    }
  }
}

// ---------------------------------------------------------------------------
// finalize stage 1: one block per (batch, class-channel); 256 threads.
// float4 loads (16 B/lane), wave shfl reduce, 4-slot LDS combine.
// ---------------------------------------------------------------------------
__global__ __launch_bounds__(256) void reduce_ch(const float* __restrict__ s,
                                                 float* __restrict__ part) {
  int blk = blockIdx.x;            // 0..159
  int b = blk / 10, o = blk - b * 10;
  const float4* ch = (const float4*)(s + ((size_t)b * 29 + 19 + o) * 4096);
  int tid = threadIdx.x;
  float4 v0 = ch[tid];
  float4 v1 = ch[tid + 256];
  float4 v2 = ch[tid + 512];
  float4 v3 = ch[tid + 768];
  float p = ((v0.x + v0.y) + (v0.z + v0.w)) + ((v1.x + v1.y) + (v1.z + v1.w)) +
            ((v2.x + v2.y) + (v2.z + v2.w)) + ((v3.x + v3.y) + (v3.z + v3.w));
#pragma unroll
  for (int d = 32; d > 0; d >>= 1) p += __shfl_down(p, d, 64);
  __shared__ float red[4];
  if ((tid & 63) == 0) red[tid >> 6] = p;
  __syncthreads();
  if (tid == 0)
    part[blk] = ((red[0] + red[1]) + (red[2] + red[3])) * (1.0f / 4096.0f);
}

// ---------------------------------------------------------------------------
// finalize stage 2: one wave per batch; lanes 0..9 hold logits; width-16
// shfl_xor max/sum (lanes 10..15 padded with -inf / 0).
// ---------------------------------------------------------------------------
__global__ __launch_bounds__(64) void softmax10(const float* __restrict__ part,
                                                float* __restrict__ out) {
  int b = blockIdx.x;
  int o = threadIdx.x;
  float v = (o < 10) ? part[b * 10 + o] : -__builtin_inff();
  float m = v;
#pragma unroll
  for (int d = 8; d > 0; d >>= 1) m = fmaxf(m, __shfl_xor(m, d, 16));
  float e = (o < 10) ? __expf(v - m) : 0.0f;
  // use expf for exactness parity with previous version
  e = (o < 10) ? expf(v - m) : 0.0f;
  float sum = e;
#pragma unroll
  for (int d = 8; d > 0; d >>= 1) sum += __shfl_xor(sum, d, 16);
  if (o < 10) out[b * 10 + o] = e / sum;
}

// ---------------------------------------------------------------------------
extern "C" void kernel_launch(void* const* d_in, const int* in_sizes, int n_in,
                              void* d_out, int out_size, void* d_ws, size_t ws_size,
                              hipStream_t stream) {
  const float* x  = (const float*)d_in[0];
  const float* w1 = (const float*)d_in[1];
  const float* b1 = (const float*)d_in[2];
  const float* w2 = (const float*)d_in[3];
  const float* w3 = (const float*)d_in[4];
  const int STEPS = 20;  // setup_inputs() fixes steps=20

  const size_t STATE = (size_t)16 * 29 * 4096;
  float* ws = (float*)d_ws;
  float* s0 = ws;
  float* s1 = ws + STATE;
  unsigned short* pw1 = (unsigned short*)(ws + 2 * STATE);  // 96*512 shorts
  unsigned short* pw2 = pw1 + 96 * 512;                      // 128*512
  unsigned short* pw3 = pw2 + 128 * 512;                     // 16*512
  float* part = (float*)(pw3 + 16 * 512);                    // 160 floats
  (void)ws_size; (void)n_in; (void)in_sizes; (void)out_size;

  prep_weights<<<256, 256, 0, stream>>>(w1, w2, w3, pw1, pw2, pw3);

  U2 hk = tf2x32(0u, 42u, 0u, 10000u);  // fold_in(key(42), 10000)
  init_state<<<(16 * 29 * 4096 + 255) / 256, 256, 0, stream>>>(x, s0, s1, hk.a, hk.b);

  for (int s = 0; s < STEPS; ++s) {
    U2 fk = tf2x32(0u, 42u, 0u, (unsigned)s);  // fold_in(key(42), step)
    float tval = (float)s / 100.0f;
    const float* in = (s & 1) ? s1 : s0;
    float* out = (s & 1) ? s0 : s1;
    dim3 grid(4, 8, 16);
    nca_step<<<grid, 256, 0, stream>>>(in, out, pw1, b1, pw2, pw3, tval, fk.a, fk.b);
  }
  reduce_ch<<<160, 256, 0, stream>>>(s0, part);
  softmax10<<<16, 64, 0, stream>>>(part, (float*)d_out);
}